// Round 1
// baseline (15644.841 us; speedup 1.0000x reference)
//
#include <hip/hip_runtime.h>
#include <math.h>

#define VOCAB 50000
#define EMB 256
#define HID 512
#define G4 2048   // 4*HID
#define KTAGS 20
#define START_TAG 18
#define END_TAG 19
#define BB 32
#define TT 256
#define NEGV -10000.0f

__device__ __forceinline__ float sigmoidf_(float x) { return 1.0f / (1.0f + expf(-x)); }

// ---------------------------------------------------------------------------
// K0: transpose Whh [2048][512] -> WhhT [512][2048] for coalesced matvec reads
// ---------------------------------------------------------------------------
__global__ __launch_bounds__(256) void k_transpose(
    const float* __restrict__ Wf_hh, const float* __restrict__ Wb_hh,
    float* __restrict__ whhT)
{
    int idx = blockIdx.x * 256 + threadIdx.x;      // 0 .. 2*512*2048-1
    int dir = (idx >= HID * G4) ? 1 : 0;
    int r   = idx - dir * HID * G4;
    int k   = r / G4;
    int j   = r - k * G4;
    const float* W = dir ? Wb_hh : Wf_hh;          // [G4][HID]
    whhT[idx] = W[(size_t)j * HID + k];
}

// ---------------------------------------------------------------------------
// K1: pre[dir][b][t][j] = emb[tok(b,t,dir)] . Wih[j,:] + bih[j] + bhh[j]
//     GEMM M=8192 (b*T+t), N=2048, K=256, one grid.z per direction.
//     Backward direction gathers x at rev_idx = (t<len ? len-1-t : t).
// ---------------------------------------------------------------------------
__global__ __launch_bounds__(256) void k_pre_gemm(
    const int* __restrict__ sentence, const int* __restrict__ lengths,
    const float* __restrict__ emb,
    const float* __restrict__ Wf_ih, const float* __restrict__ bf_ih, const float* __restrict__ bf_hh,
    const float* __restrict__ Wb_ih, const float* __restrict__ bb_ih, const float* __restrict__ bb_hh,
    float* __restrict__ pre)
{
    const int dir = blockIdx.z;
    const float* W  = dir ? Wb_ih : Wf_ih;   // [2048][256]
    const float* b1 = dir ? bb_ih : bf_ih;
    const float* b2 = dir ? bb_hh : bf_hh;
    float* C = pre + (size_t)dir * BB * TT * G4;

    __shared__ float As[64][17];
    __shared__ float Bs[64][17];

    const int tid = threadIdx.x;
    const int m0 = blockIdx.y * 64;
    const int n0 = blockIdx.x * 64;

    // load assignment: each thread loads one float4 of A and of B per k-chunk
    const int lr = tid >> 2;   // row within tile, 0..63
    const int lq = tid & 3;    // float4 slot within 16-wide k-chunk

    const int m    = m0 + lr;
    const int bidx = m >> 8;     // T == 256
    const int trow = m & 255;
    int pos = trow;
    if (dir) {
        int len = lengths[bidx];
        pos = (trow < len) ? (len - 1 - trow) : trow;
    }
    const int tok = sentence[bidx * TT + pos];
    const float* arow = emb + (size_t)tok * EMB;
    const float* wrow = W + (size_t)(n0 + lr) * EMB;

    const int ty = tid >> 4;   // 0..15 -> 4 rows each
    const int tx = tid & 15;   // 0..15 -> 4 cols each

    float acc[4][4];
    #pragma unroll
    for (int i = 0; i < 4; i++)
        #pragma unroll
        for (int j = 0; j < 4; j++) acc[i][j] = 0.f;

    for (int k0 = 0; k0 < EMB; k0 += 16) {
        float4 av = *(const float4*)(arow + k0 + lq * 4);
        float4 bv = *(const float4*)(wrow + k0 + lq * 4);
        As[lr][lq * 4 + 0] = av.x; As[lr][lq * 4 + 1] = av.y;
        As[lr][lq * 4 + 2] = av.z; As[lr][lq * 4 + 3] = av.w;
        Bs[lr][lq * 4 + 0] = bv.x; Bs[lr][lq * 4 + 1] = bv.y;
        Bs[lr][lq * 4 + 2] = bv.z; Bs[lr][lq * 4 + 3] = bv.w;
        __syncthreads();
        #pragma unroll
        for (int kk = 0; kk < 16; kk++) {
            float a[4], bb_[4];
            #pragma unroll
            for (int i = 0; i < 4; i++) a[i] = As[ty * 4 + i][kk];
            #pragma unroll
            for (int j = 0; j < 4; j++) bb_[j] = Bs[tx * 4 + j][kk];
            #pragma unroll
            for (int i = 0; i < 4; i++)
                #pragma unroll
                for (int j = 0; j < 4; j++)
                    acc[i][j] = fmaf(a[i], bb_[j], acc[i][j]);
        }
        __syncthreads();
    }

    float bs[4];
    #pragma unroll
    for (int j = 0; j < 4; j++) {
        int n = n0 + tx * 4 + j;
        bs[j] = b1[n] + b2[n];
    }
    #pragma unroll
    for (int i = 0; i < 4; i++) {
        int row = m0 + ty * 4 + i;
        float* cp = C + (size_t)row * G4 + n0 + tx * 4;
        #pragma unroll
        for (int j = 0; j < 4; j++) cp[j] = acc[i][j] + bs[j];
    }
}

// ---------------------------------------------------------------------------
// K2: LSTM recurrence. One 1024-thread WG per (b,dir). h,c in LDS.
//     Thread tid computes gate rows 2*tid, 2*tid+1 (float2-coalesced WhhT).
//     blockIdx%8 swizzle: XCDs 0-3 -> forward weights, XCDs 4-7 -> backward,
//     so each XCD's 4MB L2 holds exactly one WhhT matrix.
// ---------------------------------------------------------------------------
__global__ __launch_bounds__(1024) void k_lstm(
    const int* __restrict__ lengths,
    const float* __restrict__ whhT,  // [2][512][2048]
    const float* __restrict__ pre,   // [2][B][T][2048]
    float* __restrict__ hbuf)        // [2][B][T][512]
{
    const int g = blockIdx.x;
    const int lane8 = g & 7;
    const int dir = (lane8 >= 4) ? 1 : 0;
    const int b = (g >> 3) * 4 + (lane8 & 3);
    const int len = lengths[b];

    const float2* WT2  = (const float2*)(whhT + (size_t)dir * HID * G4);
    const float2* preB = (const float2*)(pre + ((size_t)dir * BB + b) * TT * G4);
    float* hout = hbuf + ((size_t)dir * BB + b) * TT * HID;

    __shared__ float hs[HID];
    __shared__ float cs[HID];
    __shared__ float zs[G4];

    const int tid = threadIdx.x;
    if (tid < HID) { hs[tid] = 0.f; cs[tid] = 0.f; }
    __syncthreads();

    for (int t = 0; t < len; t++) {
        float acc0 = 0.f, acc1 = 0.f;
        #pragma unroll 8
        for (int k = 0; k < HID; k++) {
            float2 w = WT2[(size_t)k * (G4 / 2) + tid];
            float hk = hs[k];
            acc0 = fmaf(w.x, hk, acc0);
            acc1 = fmaf(w.y, hk, acc1);
        }
        float2 pz = preB[(size_t)t * (G4 / 2) + tid];
        zs[2 * tid]     = acc0 + pz.x;
        zs[2 * tid + 1] = acc1 + pz.y;
        __syncthreads();
        if (tid < HID) {
            float iv = zs[tid];
            float fv = zs[HID + tid];
            float gv = zs[2 * HID + tid];
            float ov = zs[3 * HID + tid];
            float cn = sigmoidf_(fv) * cs[tid] + sigmoidf_(iv) * tanhf(gv);
            float hn = sigmoidf_(ov) * tanhf(cn);
            cs[tid] = cn;
            hs[tid] = hn;
            hout[(size_t)t * HID + tid] = hn;
        }
        __syncthreads();
    }
}

// ---------------------------------------------------------------------------
// K3: feats[b][t][k] = bout[k] + [hf(b,t) | hb_rev(b,len-1-t)] . Wout[k,:]
//     Only for t < len (feats at padded t are never read by Viterbi).
// ---------------------------------------------------------------------------
__global__ __launch_bounds__(64) void k_feats(
    const int* __restrict__ lengths,
    const float* __restrict__ hbuf,  // [2][B][T][512]
    const float* __restrict__ Wout,  // [20][1024]
    const float* __restrict__ bout,  // [20]
    float* __restrict__ feats)       // [B][T][20]
{
    const int bt = blockIdx.x;
    const int b = bt >> 8, t = bt & 255;
    const int len = lengths[b];
    if (t >= len) return;

    __shared__ float hc[2 * HID];
    const float* hf = hbuf + ((size_t)b * TT + t) * HID;
    const float* hb = hbuf + ((size_t)(BB + b) * TT + (len - 1 - t)) * HID;
    const int tid = threadIdx.x;
    for (int i = tid; i < HID / 4; i += 64)
        ((float4*)hc)[i] = ((const float4*)hf)[i];
    for (int i = tid; i < HID / 4; i += 64)
        ((float4*)(hc + HID))[i] = ((const float4*)hb)[i];
    __syncthreads();

    if (tid < KTAGS) {
        float d = bout[tid];
        const float* wr = Wout + (size_t)tid * (2 * HID);
        #pragma unroll 4
        for (int i = 0; i < 2 * HID; i++) d = fmaf(hc[i], wr[i], d);
        feats[(size_t)bt * KTAGS + tid] = d;
    }
}

// ---------------------------------------------------------------------------
// K4: Viterbi forward (t < len only) + terminal + right-aligned backtrack.
//     One 64-thread block per batch element. argmax = first-max (strict >).
// ---------------------------------------------------------------------------
__global__ __launch_bounds__(64) void k_viterbi(
    const int* __restrict__ lengths,
    const float* __restrict__ trans,  // [20][20]
    const float* __restrict__ feats,  // [B][T][20]
    int* __restrict__ bptr,           // [B][T][20]
    float* __restrict__ out)          // [32 scores][32*257 path]
{
    const int b = blockIdx.x;
    const int len = lengths[b];
    const int tid = threadIdx.x;

    __shared__ float tr[KTAGS * KTAGS];
    __shared__ float fv[KTAGS], fvn[KTAGS];

    for (int i = tid; i < KTAGS * KTAGS; i += 64) tr[i] = trans[i];
    if (tid < KTAGS) fv[tid] = (tid == START_TAG) ? 0.f : NEGV;
    __syncthreads();

    for (int t = 0; t < len; t++) {
        if (tid < KTAGS) {
            float best = -1e30f; int bi = 0;
            #pragma unroll
            for (int p = 0; p < KTAGS; p++) {
                float s = fv[p] + tr[tid * KTAGS + p];
                if (s > best) { best = s; bi = p; }
            }
            fvn[tid] = best + feats[((size_t)b * TT + t) * KTAGS + tid];
            bptr[((size_t)b * TT + t) * KTAGS + tid] = bi;
        }
        __syncthreads();
        if (tid < KTAGS) fv[tid] = fvn[tid];
        __syncthreads();
    }

    if (tid < KTAGS) fvn[tid] = fv[tid] + tr[END_TAG * KTAGS + tid];
    __syncthreads();

    if (tid == 0) {
        int bt_ = 0; float best = fvn[0];
        for (int k = 1; k < KTAGS; k++)
            if (fvn[k] > best) { best = fvn[k]; bt_ = k; }
        out[b] = best;                              // path_score [B,1]
        float* path = out + BB + (size_t)b * (TT + 1);
        path[TT] = (float)bt_;
        int cur = bt_;
        for (int t = TT - 1; t >= 0; t--) {
            int src = t - (TT - len);
            if (src >= 0) cur = bptr[((size_t)b * TT + src) * KTAGS + cur];
            else          cur = KTAGS;              // sentinel 20
            path[t] = (float)cur;
        }
    }
}

// ---------------------------------------------------------------------------
extern "C" void kernel_launch(void* const* d_in, const int* in_sizes, int n_in,
                              void* d_out, int out_size, void* d_ws, size_t ws_size,
                              hipStream_t stream) {
    const int*   sentence = (const int*)d_in[0];
    const int*   lengths  = (const int*)d_in[1];
    const float* emb      = (const float*)d_in[2];
    const float* Wf_ih    = (const float*)d_in[3];
    const float* Wf_hh    = (const float*)d_in[4];
    const float* bf_ih    = (const float*)d_in[5];
    const float* bf_hh    = (const float*)d_in[6];
    const float* Wb_ih    = (const float*)d_in[7];
    const float* Wb_hh    = (const float*)d_in[8];
    const float* bb_ih    = (const float*)d_in[9];
    const float* bb_hh    = (const float*)d_in[10];
    const float* Wout     = (const float*)d_in[11];
    const float* bout     = (const float*)d_in[12];
    const float* trans    = (const float*)d_in[13];
    float* out = (float*)d_out;

    // workspace layout (floats)
    float* pre   = (float*)d_ws;                       // 2*32*256*2048 = 33,554,432
    float* whhT  = pre  + (size_t)2 * BB * TT * G4;    // 2*512*2048   =  2,097,152
    float* hbuf  = whhT + (size_t)2 * HID * G4;        // 2*32*256*512 =  8,388,608
    float* feats = hbuf + (size_t)2 * BB * TT * HID;   // 32*256*20    =    163,840
    int*   bptr  = (int*)(feats + (size_t)BB * TT * KTAGS); // 163,840 ints
    // total ~ 169.3 MB

    hipLaunchKernelGGL(k_transpose, dim3((2 * HID * G4) / 256), dim3(256), 0, stream,
                       Wf_hh, Wb_hh, whhT);
    hipLaunchKernelGGL(k_pre_gemm, dim3(G4 / 64, (BB * TT) / 64, 2), dim3(256), 0, stream,
                       sentence, lengths, emb, Wf_ih, bf_ih, bf_hh, Wb_ih, bb_ih, bb_hh, pre);
    hipLaunchKernelGGL(k_lstm, dim3(64), dim3(1024), 0, stream,
                       lengths, whhT, pre, hbuf);
    hipLaunchKernelGGL(k_feats, dim3(BB * TT), dim3(64), 0, stream,
                       lengths, hbuf, Wout, bout, feats);
    hipLaunchKernelGGL(k_viterbi, dim3(BB), dim3(64), 0, stream,
                       lengths, trans, feats, bptr, out);
}

// Round 3
// 9376.154 us; speedup vs baseline: 1.6686x; 1.6686x over previous
//
#include <hip/hip_runtime.h>
#include <math.h>

#define VOCAB 50000
#define EMB 256
#define HID 512
#define G4 2048   // 4*HID
#define KTAGS 20
#define START_TAG 18
#define END_TAG 19
#define BB 32
#define TT 256
#define NEGV -10000.0f
#define NWG 128

__device__ __forceinline__ float sigmoidf_(float x) { return 1.0f / (1.0f + expf(-x)); }

// ---------------------------------------------------------------------------
// K1: pre[dir][b][t][j] = emb[tok(b,t,dir)] . Wih[j,:] + bih[j] + bhh[j]
// ---------------------------------------------------------------------------
__global__ __launch_bounds__(256) void k_pre_gemm(
    const int* __restrict__ sentence, const int* __restrict__ lengths,
    const float* __restrict__ emb,
    const float* __restrict__ Wf_ih, const float* __restrict__ bf_ih, const float* __restrict__ bf_hh,
    const float* __restrict__ Wb_ih, const float* __restrict__ bb_ih, const float* __restrict__ bb_hh,
    float* __restrict__ pre)
{
    const int dir = blockIdx.z;
    const float* W  = dir ? Wb_ih : Wf_ih;   // [2048][256]
    const float* b1 = dir ? bb_ih : bf_ih;
    const float* b2 = dir ? bb_hh : bf_hh;
    float* C = pre + (size_t)dir * BB * TT * G4;

    __shared__ float As[64][17];
    __shared__ float Bs[64][17];

    const int tid = threadIdx.x;
    const int m0 = blockIdx.y * 64;
    const int n0 = blockIdx.x * 64;

    const int lr = tid >> 2;
    const int lq = tid & 3;

    const int m    = m0 + lr;
    const int bidx = m >> 8;
    const int trow = m & 255;
    int pos = trow;
    if (dir) {
        int len = lengths[bidx];
        pos = (trow < len) ? (len - 1 - trow) : trow;
    }
    const int tok = sentence[bidx * TT + pos];
    const float* arow = emb + (size_t)tok * EMB;
    const float* wrow = W + (size_t)(n0 + lr) * EMB;

    const int ty = tid >> 4;
    const int tx = tid & 15;

    float acc[4][4];
    #pragma unroll
    for (int i = 0; i < 4; i++)
        #pragma unroll
        for (int j = 0; j < 4; j++) acc[i][j] = 0.f;

    for (int k0 = 0; k0 < EMB; k0 += 16) {
        float4 av = *(const float4*)(arow + k0 + lq * 4);
        float4 bv = *(const float4*)(wrow + k0 + lq * 4);
        As[lr][lq * 4 + 0] = av.x; As[lr][lq * 4 + 1] = av.y;
        As[lr][lq * 4 + 2] = av.z; As[lr][lq * 4 + 3] = av.w;
        Bs[lr][lq * 4 + 0] = bv.x; Bs[lr][lq * 4 + 1] = bv.y;
        Bs[lr][lq * 4 + 2] = bv.z; Bs[lr][lq * 4 + 3] = bv.w;
        __syncthreads();
        #pragma unroll
        for (int kk = 0; kk < 16; kk++) {
            float a[4], bb_[4];
            #pragma unroll
            for (int i = 0; i < 4; i++) a[i] = As[ty * 4 + i][kk];
            #pragma unroll
            for (int j = 0; j < 4; j++) bb_[j] = Bs[tx * 4 + j][kk];
            #pragma unroll
            for (int i = 0; i < 4; i++)
                #pragma unroll
                for (int j = 0; j < 4; j++)
                    acc[i][j] = fmaf(a[i], bb_[j], acc[i][j]);
        }
        __syncthreads();
    }

    float bs[4];
    #pragma unroll
    for (int j = 0; j < 4; j++) {
        int n = n0 + tx * 4 + j;
        bs[j] = b1[n] + b2[n];
    }
    #pragma unroll
    for (int i = 0; i < 4; i++) {
        int row = m0 + ty * 4 + i;
        float* cp = C + (size_t)row * G4 + n0 + tx * 4;
        #pragma unroll
        for (int j = 0; j < 4; j++) cp[j] = acc[i][j] + bs[j];
    }
}

// ---------------------------------------------------------------------------
// K2: persistent batched LSTM. 128 WGs x 256 thr, all co-resident.
//   WG = (dir, slice of 8 hidden units). Wave = 2 hidden units (8 gate-cols).
//   Lane (kg = lane>>3, x = lane&7): owns Whh[col(x)][kg*64 .. +64) in 64 VGPRs
//   (loaded ONCE). Per step: stage h(t) for all 32 b into bank-skewed LDS,
//   per-b 64-FMA partial dot + 3-step shfl_xor reduce over kg, gate math with
//   c in a register, h' -> ping-pong global buffer, fenced grid barrier.
// ---------------------------------------------------------------------------
__global__ __launch_bounds__(256, 1) void k_lstm_persist(
    const int* __restrict__ lengths,
    const float* __restrict__ Wf_hh, const float* __restrict__ Wb_hh,
    const float* __restrict__ pre,     // [2][32][256][2048]
    float* __restrict__ hping,         // [2 buf][2 dir][32][512]
    unsigned* __restrict__ bar,
    float* __restrict__ hbuf)          // [2][32][256][512]
{
    const int wg = blockIdx.x;
    const int dir = wg >> 6;
    const int slice = wg & 63;
    const int tid = threadIdx.x;
    const int wave = tid >> 6;
    const int lane = tid & 63;
    // dot-phase identity
    const int kg = lane >> 3;          // k-group 0..7  (k range kg*64..+64)
    const int x  = lane & 7;           // 0..7 = (u2, gate)
    const int u2 = x >> 2;
    const int gate = x & 3;
    const int ubase = slice * 8 + wave * 2;
    const int col = gate * HID + ubase + u2;   // Whh row
    // gate-phase identity
    const int gu2 = lane >> 5;         // 0..1
    const int gb  = lane & 31;         // batch element
    const int gu  = ubase + gu2;       // global hidden unit

    const float* Whh = dir ? Wb_hh : Wf_hh;
    float4 w[16];
    {
        const float4* wrow = (const float4*)(Whh + (size_t)col * HID + kg * 64);
        #pragma unroll
        for (int j = 0; j < 16; j++) w[j] = wrow[j];
    }

    __shared__ float hs[32 * 544];     // skewed: h[b][k] at b*544 + k + 4*(k>>6)
    __shared__ float zw[4][32][8];
    __shared__ int lens[32];
    if (tid < 32) lens[tid] = lengths[tid];
    __syncthreads();
    const int glen = lens[gb];

    float c_reg = 0.f;
    const float* preD = pre + (size_t)dir * BB * TT * G4;
    float* houtD = hbuf + (size_t)dir * BB * TT * HID;

    for (int t = 0; t < TT; t++) {
        // ---- stage h(t): 64KB coalesced global -> skewed LDS ----
        {
            const float4* src = (const float4*)(hping + (size_t)((t & 1) * 2 + dir) * BB * HID);
            #pragma unroll
            for (int it = 0; it < 16; it++) {
                int idx = tid + it * 256;   // float4 index 0..4095
                int b = idx >> 7;
                int kq = idx & 127;
                *(float4*)&hs[b * 544 + kq * 4 + (kq >> 4) * 4] = src[idx];
            }
        }
        __syncthreads();

        // ---- early-issue pre-activation loads (used in gate phase) ----
        float p0 = 0.f, p1 = 0.f, p2 = 0.f, p3 = 0.f;
        if (t < glen) {
            const float* pb = preD + ((size_t)gb * TT + t) * G4 + gu;
            p0 = pb[0]; p1 = pb[HID]; p2 = pb[2 * HID]; p3 = pb[3 * HID];
        }

        // ---- dot phase: z[b][col] partials over lane's 64-k range ----
        for (int b = 0; b < 32; b++) {
            if (t >= lens[b]) continue;
            const float* hb = &hs[b * 544 + kg * 68];
            float a0 = 0.f, a1 = 0.f, a2 = 0.f, a3 = 0.f;
            #pragma unroll
            for (int j = 0; j < 16; j += 4) {
                float4 h0 = *(const float4*)(hb + 4 * j);
                float4 h1 = *(const float4*)(hb + 4 * j + 4);
                float4 h2 = *(const float4*)(hb + 4 * j + 8);
                float4 h3 = *(const float4*)(hb + 4 * j + 12);
                a0 = fmaf(w[j].x,     h0.x, a0); a0 = fmaf(w[j].y,     h0.y, a0);
                a0 = fmaf(w[j].z,     h0.z, a0); a0 = fmaf(w[j].w,     h0.w, a0);
                a1 = fmaf(w[j + 1].x, h1.x, a1); a1 = fmaf(w[j + 1].y, h1.y, a1);
                a1 = fmaf(w[j + 1].z, h1.z, a1); a1 = fmaf(w[j + 1].w, h1.w, a1);
                a2 = fmaf(w[j + 2].x, h2.x, a2); a2 = fmaf(w[j + 2].y, h2.y, a2);
                a2 = fmaf(w[j + 2].z, h2.z, a2); a2 = fmaf(w[j + 2].w, h2.w, a2);
                a3 = fmaf(w[j + 3].x, h3.x, a3); a3 = fmaf(w[j + 3].y, h3.y, a3);
                a3 = fmaf(w[j + 3].z, h3.z, a3); a3 = fmaf(w[j + 3].w, h3.w, a3);
            }
            float acc = (a0 + a1) + (a2 + a3);
            acc += __shfl_xor(acc, 8);
            acc += __shfl_xor(acc, 16);
            acc += __shfl_xor(acc, 32);
            if (kg == 0) zw[wave][b][x] = acc;
        }

        // ---- gate phase: lane = (gu2, gb), c in register ----
        if (t < glen) {
            float4 zz = *(float4*)&zw[wave][gb][gu2 * 4];
            float iv = zz.x + p0, fv = zz.y + p1, gv = zz.z + p2, ov = zz.w + p3;
            float cn = sigmoidf_(fv) * c_reg + sigmoidf_(iv) * tanhf(gv);
            float hn = sigmoidf_(ov) * tanhf(cn);
            c_reg = cn;
            houtD[((size_t)gb * TT + t) * HID + gu] = hn;
            hping[((size_t)((t + 1) & 1) * 2 + dir) * BB * HID + (size_t)gb * HID + gu] = hn;
        }

        // ---- fenced grid barrier ----
        if (t < TT - 1) {
            __threadfence();
            __syncthreads();
            if (tid == 0) {
                __hip_atomic_fetch_add(bar, 1u, __ATOMIC_RELAXED, __HIP_MEMORY_SCOPE_AGENT);
                unsigned tgt = (unsigned)(t + 1) * (unsigned)NWG;
                while (__hip_atomic_load(bar, __ATOMIC_RELAXED, __HIP_MEMORY_SCOPE_AGENT) < tgt)
                    __builtin_amdgcn_s_sleep(1);
            }
            __syncthreads();
            __threadfence();
        }
    }
}

// ---------------------------------------------------------------------------
// K3: feats[b][t][k] = bout[k] + [hf(b,t) | hb_rev(b,len-1-t)] . Wout[k,:]
// ---------------------------------------------------------------------------
__global__ __launch_bounds__(64) void k_feats(
    const int* __restrict__ lengths,
    const float* __restrict__ hbuf,  // [2][B][T][512]
    const float* __restrict__ Wout,  // [20][1024]
    const float* __restrict__ bout,  // [20]
    float* __restrict__ feats)       // [B][T][20]
{
    const int bt = blockIdx.x;
    const int b = bt >> 8, t = bt & 255;
    const int len = lengths[b];
    if (t >= len) return;

    __shared__ float hc[2 * HID];
    const float* hf = hbuf + ((size_t)b * TT + t) * HID;
    const float* hb = hbuf + ((size_t)(BB + b) * TT + (len - 1 - t)) * HID;
    const int tid = threadIdx.x;
    for (int i = tid; i < HID / 4; i += 64)
        ((float4*)hc)[i] = ((const float4*)hf)[i];
    for (int i = tid; i < HID / 4; i += 64)
        ((float4*)(hc + HID))[i] = ((const float4*)hb)[i];
    __syncthreads();

    if (tid < KTAGS) {
        float d = bout[tid];
        const float* wr = Wout + (size_t)tid * (2 * HID);
        #pragma unroll 4
        for (int i = 0; i < 2 * HID; i++) d = fmaf(hc[i], wr[i], d);
        feats[(size_t)bt * KTAGS + tid] = d;
    }
}

// ---------------------------------------------------------------------------
// K4: Viterbi forward + terminal + right-aligned backtrack.
// ---------------------------------------------------------------------------
__global__ __launch_bounds__(64) void k_viterbi(
    const int* __restrict__ lengths,
    const float* __restrict__ trans,  // [20][20]
    const float* __restrict__ feats,  // [B][T][20]
    int* __restrict__ bptr,           // [B][T][20]
    float* __restrict__ out)          // [32 scores][32*257 path]
{
    const int b = blockIdx.x;
    const int len = lengths[b];
    const int tid = threadIdx.x;

    __shared__ float tr[KTAGS * KTAGS];
    __shared__ float fv[KTAGS], fvn[KTAGS];

    for (int i = tid; i < KTAGS * KTAGS; i += 64) tr[i] = trans[i];
    if (tid < KTAGS) fv[tid] = (tid == START_TAG) ? 0.f : NEGV;
    __syncthreads();

    for (int t = 0; t < len; t++) {
        if (tid < KTAGS) {
            float best = -1e30f; int bi = 0;
            #pragma unroll
            for (int p = 0; p < KTAGS; p++) {
                float s = fv[p] + tr[tid * KTAGS + p];
                if (s > best) { best = s; bi = p; }
            }
            fvn[tid] = best + feats[((size_t)b * TT + t) * KTAGS + tid];
            bptr[((size_t)b * TT + t) * KTAGS + tid] = bi;
        }
        __syncthreads();
        if (tid < KTAGS) fv[tid] = fvn[tid];
        __syncthreads();
    }

    if (tid < KTAGS) fvn[tid] = fv[tid] + tr[END_TAG * KTAGS + tid];
    __syncthreads();

    if (tid == 0) {
        int bt_ = 0; float best = fvn[0];
        for (int k = 1; k < KTAGS; k++)
            if (fvn[k] > best) { best = fvn[k]; bt_ = k; }
        out[b] = best;
        float* path = out + BB + (size_t)b * (TT + 1);
        path[TT] = (float)bt_;
        int cur = bt_;
        for (int t = TT - 1; t >= 0; t--) {
            int src = t - (TT - len);
            if (src >= 0) cur = bptr[((size_t)b * TT + src) * KTAGS + cur];
            else          cur = KTAGS;
            path[t] = (float)cur;
        }
    }
}

// ---------------------------------------------------------------------------
extern "C" void kernel_launch(void* const* d_in, const int* in_sizes, int n_in,
                              void* d_out, int out_size, void* d_ws, size_t ws_size,
                              hipStream_t stream) {
    const int*   sentence = (const int*)d_in[0];
    const int*   lengths  = (const int*)d_in[1];
    const float* emb      = (const float*)d_in[2];
    const float* Wf_ih    = (const float*)d_in[3];
    const float* Wf_hh    = (const float*)d_in[4];
    const float* bf_ih    = (const float*)d_in[5];
    const float* bf_hh    = (const float*)d_in[6];
    const float* Wb_ih    = (const float*)d_in[7];
    const float* Wb_hh    = (const float*)d_in[8];
    const float* bb_ih    = (const float*)d_in[9];
    const float* bb_hh    = (const float*)d_in[10];
    const float* Wout     = (const float*)d_in[11];
    const float* bout     = (const float*)d_in[12];
    const float* trans    = (const float*)d_in[13];
    float* out = (float*)d_out;

    // workspace layout
    float*    hping = (float*)d_ws;                            // 65536 floats (256KB)
    unsigned* bar   = (unsigned*)((char*)d_ws + 65536 * 4);    // 256B region
    float*    pre   = (float*)((char*)d_ws + 65536 * 4 + 256); // 2*32*256*2048 floats
    float*    hbuf  = pre + (size_t)2 * BB * TT * G4;          // 2*32*256*512
    float*    feats = hbuf + (size_t)2 * BB * TT * HID;        // 32*256*20
    int*      bptr  = (int*)(feats + (size_t)BB * TT * KTAGS); // 32*256*20

    // zero ping-pong h buffers + barrier counter (every launch; ws re-poisoned)
    (void)hipMemsetAsync(d_ws, 0, 65536 * 4 + 256, stream);

    hipLaunchKernelGGL(k_pre_gemm, dim3(G4 / 64, (BB * TT) / 64, 2), dim3(256), 0, stream,
                       sentence, lengths, emb, Wf_ih, bf_ih, bf_hh, Wb_ih, bb_ih, bb_hh, pre);
    hipLaunchKernelGGL(k_lstm_persist, dim3(NWG), dim3(256), 0, stream,
                       lengths, Wf_hh, Wb_hh, pre, hping, bar, hbuf);
    hipLaunchKernelGGL(k_feats, dim3(BB * TT), dim3(64), 0, stream,
                       lengths, hbuf, Wout, bout, feats);
    hipLaunchKernelGGL(k_viterbi, dim3(BB), dim3(64), 0, stream,
                       lengths, trans, feats, bptr, out);
}

// Round 4
// 4470.594 us; speedup vs baseline: 3.4995x; 2.0973x over previous
//
#include <hip/hip_runtime.h>
#include <math.h>

#define VOCAB 50000
#define EMB 256
#define HID 512
#define G4 2048   // 4*HID
#define KTAGS 20
#define START_TAG 18
#define END_TAG 19
#define BB 32
#define TT 256
#define NEGV -10000.0f
#define HSROW 644   // 640 phys floats per b + 4 skew

__device__ __forceinline__ float sigmoidf_(float x) { return 1.0f / (1.0f + expf(-x)); }

// ---------------------------------------------------------------------------
// K1: pre[dir][b][t][j] = emb[tok(b,t,dir)] . Wih[j,:] + bih[j] + bhh[j]
//     Tiles whose 64 rows are all t >= len[b] are skipped (never read).
// ---------------------------------------------------------------------------
__global__ __launch_bounds__(256) void k_pre_gemm(
    const int* __restrict__ sentence, const int* __restrict__ lengths,
    const float* __restrict__ emb,
    const float* __restrict__ Wf_ih, const float* __restrict__ bf_ih, const float* __restrict__ bf_hh,
    const float* __restrict__ Wb_ih, const float* __restrict__ bb_ih, const float* __restrict__ bb_hh,
    float* __restrict__ pre)
{
    const int m0 = blockIdx.y * 64;
    if ((m0 & 255) >= lengths[m0 >> 8]) return;   // whole tile padded -> unread

    const int dir = blockIdx.z;
    const float* W  = dir ? Wb_ih : Wf_ih;   // [2048][256]
    const float* b1 = dir ? bb_ih : bf_ih;
    const float* b2 = dir ? bb_hh : bf_hh;
    float* C = pre + (size_t)dir * BB * TT * G4;

    __shared__ float As[64][17];
    __shared__ float Bs[64][17];

    const int tid = threadIdx.x;
    const int n0 = blockIdx.x * 64;

    const int lr = tid >> 2;
    const int lq = tid & 3;

    const int m    = m0 + lr;
    const int bidx = m >> 8;
    const int trow = m & 255;
    int pos = trow;
    if (dir) {
        int len = lengths[bidx];
        pos = (trow < len) ? (len - 1 - trow) : trow;
    }
    const int tok = sentence[bidx * TT + pos];
    const float* arow = emb + (size_t)tok * EMB;
    const float* wrow = W + (size_t)(n0 + lr) * EMB;

    const int ty = tid >> 4;
    const int tx = tid & 15;

    float acc[4][4];
    #pragma unroll
    for (int i = 0; i < 4; i++)
        #pragma unroll
        for (int j = 0; j < 4; j++) acc[i][j] = 0.f;

    for (int k0 = 0; k0 < EMB; k0 += 16) {
        float4 av = *(const float4*)(arow + k0 + lq * 4);
        float4 bv = *(const float4*)(wrow + k0 + lq * 4);
        As[lr][lq * 4 + 0] = av.x; As[lr][lq * 4 + 1] = av.y;
        As[lr][lq * 4 + 2] = av.z; As[lr][lq * 4 + 3] = av.w;
        Bs[lr][lq * 4 + 0] = bv.x; Bs[lr][lq * 4 + 1] = bv.y;
        Bs[lr][lq * 4 + 2] = bv.z; Bs[lr][lq * 4 + 3] = bv.w;
        __syncthreads();
        #pragma unroll
        for (int kk = 0; kk < 16; kk++) {
            float a[4], bb_[4];
            #pragma unroll
            for (int i = 0; i < 4; i++) a[i] = As[ty * 4 + i][kk];
            #pragma unroll
            for (int j = 0; j < 4; j++) bb_[j] = Bs[tx * 4 + j][kk];
            #pragma unroll
            for (int i = 0; i < 4; i++)
                #pragma unroll
                for (int j = 0; j < 4; j++)
                    acc[i][j] = fmaf(a[i], bb_[j], acc[i][j]);
        }
        __syncthreads();
    }

    float bs[4];
    #pragma unroll
    for (int j = 0; j < 4; j++) {
        int n = n0 + tx * 4 + j;
        bs[j] = b1[n] + b2[n];
    }
    #pragma unroll
    for (int i = 0; i < 4; i++) {
        int row = m0 + ty * 4 + i;
        float* cp = C + (size_t)row * G4 + n0 + tx * 4;
        #pragma unroll
        for (int j = 0; j < 4; j++) cp[j] = acc[i][j] + bs[j];
    }
}

// ---------------------------------------------------------------------------
// K2: persistent batched LSTM, fence-free sc1 protocol.
//   128 WGs x 256 thr (1/CU). WG = (dir, 8 hidden units). Thread (dot phase)
//   = (kg = 16-float k-slice, unit): holds the 4 gate rows of ONE unit over
//   its k-slice = 64 weights in VGPRs (loaded once). Per b: 4 ds_read_b128 of
//   h-slice + 64 FMA + 6-shfl transpose-reduce -> lane owns one gate's full z.
//   Cross-WG h exchange via __hip_atomic_{load,store}(RELAXED, AGENT) (= sc1,
//   MALL-coherent, no L2 writeback/invalidate). Per-dir barrier counter.
// ---------------------------------------------------------------------------
__global__ __launch_bounds__(256, 1) void k_lstm_persist(
    const int* __restrict__ lengths,
    const float* __restrict__ Wf_hh, const float* __restrict__ Wb_hh,
    const float* __restrict__ pre,     // [2][32][256][2048]
    float* __restrict__ hping,         // [2 parity][2 dir][32][512]
    unsigned* __restrict__ bar,        // bar[0]=dir0, bar[32]=dir1
    float* __restrict__ hbuf)          // [2][32][256][512]
{
    const int wg = blockIdx.x;
    const int dir = wg >> 6;
    const int slice = wg & 63;
    const int tid = threadIdx.x;
    const int wave = tid >> 6;
    const int lane = tid & 63;
    // dot identity
    const int kg = lane >> 1;              // 0..31, k range [kg*16, kg*16+16)
    const int x  = lane & 1;               // unit parity within wave
    const int u_loc  = wave * 2 + x;       // 0..7
    const int u_glob = slice * 8 + u_loc;  // 0..511
    // gate identity
    const int gu2 = lane >> 5;             // 0..1
    const int gb  = lane & 31;             // batch
    const int gul = wave * 2 + gu2;
    const int gug = slice * 8 + gul;
    // staging identity
    const int sb = tid >> 3;               // batch 0..31
    const int sq = tid & 7;                // 64-float chunk

    const float* Whh = dir ? Wb_hh : Wf_hh;
    float4 w[4][4];                        // [gate c][float4 j]
    #pragma unroll
    for (int c = 0; c < 4; c++) {
        const float4* wr = (const float4*)(Whh + (size_t)(c * HID + u_glob) * HID + kg * 16);
        #pragma unroll
        for (int j = 0; j < 4; j++) w[c][j] = wr[j];
    }

    __shared__ float hs[32 * HSROW];       // h[b][k] at b*644 + k + 4*(k>>4)
    __shared__ float zw[8 * 132];          // zw[u_loc][c*33 + b]
    __shared__ int lens[32];
    if (tid < 32) lens[tid] = lengths[tid];
    __syncthreads();
    const int glen = lens[gb];

    float c_reg = 0.f;
    const float* preD = pre + (size_t)dir * BB * TT * G4;
    float* houtD = hbuf + (size_t)dir * BB * TT * HID;
    unsigned* mybar = bar + dir * 32;

    for (int t = 0; t < TT; t++) {
        // ---- stage h(t): sc1 (MALL-coherent) loads -> skewed LDS ----
        if (t < lens[sb]) {
            const float* src = hping + ((size_t)((t & 1) * 2 + dir) * BB + sb) * HID + sq * 64;
            float* dst = &hs[sb * HSROW + sq * 80];
            #pragma unroll
            for (int i = 0; i < 4; i++) {
                float tmp[16];
                #pragma unroll
                for (int m = 0; m < 16; m++)
                    tmp[m] = __hip_atomic_load(src + i * 16 + m,
                                               __ATOMIC_RELAXED, __HIP_MEMORY_SCOPE_AGENT);
                float* d = dst + i * 20;
                #pragma unroll
                for (int q = 0; q < 4; q++)
                    *(float4*)(d + q * 4) = *(const float4*)(tmp + q * 4);
            }
        }
        __syncthreads();

        // ---- early-issue pre-activation loads ----
        float p0 = 0.f, p1 = 0.f, p2 = 0.f, p3 = 0.f;
        if (t < glen) {
            const float* pb = preD + ((size_t)gb * TT + t) * G4 + gug;
            p0 = pb[0]; p1 = pb[HID]; p2 = pb[2 * HID]; p3 = pb[3 * HID];
        }

        // ---- dot phase ----
        for (int b = 0; b < 32; b++) {
            if (t >= lens[b]) continue;
            const float* hb = &hs[b * HSROW + kg * 20];
            float4 h0 = *(const float4*)(hb);
            float4 h1 = *(const float4*)(hb + 4);
            float4 h2 = *(const float4*)(hb + 8);
            float4 h3 = *(const float4*)(hb + 12);
            float a0 = 0.f, a1 = 0.f, a2 = 0.f, a3 = 0.f;
            #pragma unroll
            for (int comp = 0; comp < 1; comp++) {   // (flattened below)
                a0 = fmaf(w[0][0].x, h0.x, a0); a0 = fmaf(w[0][0].y, h0.y, a0);
                a0 = fmaf(w[0][0].z, h0.z, a0); a0 = fmaf(w[0][0].w, h0.w, a0);
                a0 = fmaf(w[0][1].x, h1.x, a0); a0 = fmaf(w[0][1].y, h1.y, a0);
                a0 = fmaf(w[0][1].z, h1.z, a0); a0 = fmaf(w[0][1].w, h1.w, a0);
                a0 = fmaf(w[0][2].x, h2.x, a0); a0 = fmaf(w[0][2].y, h2.y, a0);
                a0 = fmaf(w[0][2].z, h2.z, a0); a0 = fmaf(w[0][2].w, h2.w, a0);
                a0 = fmaf(w[0][3].x, h3.x, a0); a0 = fmaf(w[0][3].y, h3.y, a0);
                a0 = fmaf(w[0][3].z, h3.z, a0); a0 = fmaf(w[0][3].w, h3.w, a0);

                a1 = fmaf(w[1][0].x, h0.x, a1); a1 = fmaf(w[1][0].y, h0.y, a1);
                a1 = fmaf(w[1][0].z, h0.z, a1); a1 = fmaf(w[1][0].w, h0.w, a1);
                a1 = fmaf(w[1][1].x, h1.x, a1); a1 = fmaf(w[1][1].y, h1.y, a1);
                a1 = fmaf(w[1][1].z, h1.z, a1); a1 = fmaf(w[1][1].w, h1.w, a1);
                a1 = fmaf(w[1][2].x, h2.x, a1); a1 = fmaf(w[1][2].y, h2.y, a1);
                a1 = fmaf(w[1][2].z, h2.z, a1); a1 = fmaf(w[1][2].w, h2.w, a1);
                a1 = fmaf(w[1][3].x, h3.x, a1); a1 = fmaf(w[1][3].y, h3.y, a1);
                a1 = fmaf(w[1][3].z, h3.z, a1); a1 = fmaf(w[1][3].w, h3.w, a1);

                a2 = fmaf(w[2][0].x, h0.x, a2); a2 = fmaf(w[2][0].y, h0.y, a2);
                a2 = fmaf(w[2][0].z, h0.z, a2); a2 = fmaf(w[2][0].w, h0.w, a2);
                a2 = fmaf(w[2][1].x, h1.x, a2); a2 = fmaf(w[2][1].y, h1.y, a2);
                a2 = fmaf(w[2][1].z, h1.z, a2); a2 = fmaf(w[2][1].w, h1.w, a2);
                a2 = fmaf(w[2][2].x, h2.x, a2); a2 = fmaf(w[2][2].y, h2.y, a2);
                a2 = fmaf(w[2][2].z, h2.z, a2); a2 = fmaf(w[2][2].w, h2.w, a2);
                a2 = fmaf(w[2][3].x, h3.x, a2); a2 = fmaf(w[2][3].y, h3.y, a2);
                a2 = fmaf(w[2][3].z, h3.z, a2); a2 = fmaf(w[2][3].w, h3.w, a2);

                a3 = fmaf(w[3][0].x, h0.x, a3); a3 = fmaf(w[3][0].y, h0.y, a3);
                a3 = fmaf(w[3][0].z, h0.z, a3); a3 = fmaf(w[3][0].w, h0.w, a3);
                a3 = fmaf(w[3][1].x, h1.x, a3); a3 = fmaf(w[3][1].y, h1.y, a3);
                a3 = fmaf(w[3][1].z, h1.z, a3); a3 = fmaf(w[3][1].w, h1.w, a3);
                a3 = fmaf(w[3][2].x, h2.x, a3); a3 = fmaf(w[3][2].y, h2.y, a3);
                a3 = fmaf(w[3][2].z, h2.z, a3); a3 = fmaf(w[3][2].w, h2.w, a3);
                a3 = fmaf(w[3][3].x, h3.x, a3); a3 = fmaf(w[3][3].y, h3.y, a3);
                a3 = fmaf(w[3][3].z, h3.z, a3); a3 = fmaf(w[3][3].w, h3.w, a3);
            }
            // transpose-butterfly reduce over 32 kg-lanes (lane bits 5..1)
            bool lo32 = (lane & 32) == 0;
            float tA = __shfl_xor(lo32 ? a2 : a0, 32);
            float tB = __shfl_xor(lo32 ? a3 : a1, 32);
            float rA = (lo32 ? a0 : a2) + tA;   // gate 0 or 2
            float rB = (lo32 ? a1 : a3) + tB;   // gate 1 or 3
            bool lo16 = (lane & 16) == 0;
            float tC = __shfl_xor(lo16 ? rB : rA, 16);
            float r  = (lo16 ? rA : rB) + tC;   // gate (lane>>4)&3
            r += __shfl_xor(r, 8);
            r += __shfl_xor(r, 4);
            r += __shfl_xor(r, 2);
            if ((lane & 14) == 0)
                zw[u_loc * 132 + ((lane >> 4) & 3) * 33 + b] = r;
        }

        // ---- gate phase: lane = (gu2, gb) ----
        if (t < glen) {
            float zi = zw[gul * 132 +  0 + gb];
            float zf = zw[gul * 132 + 33 + gb];
            float zg = zw[gul * 132 + 66 + gb];
            float zo = zw[gul * 132 + 99 + gb];
            float iv = zi + p0, fv = zf + p1, gv = zg + p2, ov = zo + p3;
            float cn = sigmoidf_(fv) * c_reg + sigmoidf_(iv) * tanhf(gv);
            float hn = sigmoidf_(ov) * tanhf(cn);
            c_reg = cn;
            houtD[((size_t)gb * TT + t) * HID + gug] = hn;
            __hip_atomic_store(
                hping + ((size_t)(((t + 1) & 1) * 2 + dir) * BB + gb) * HID + gug,
                hn, __ATOMIC_RELAXED, __HIP_MEMORY_SCOPE_AGENT);
        }

        // ---- fence-free grid barrier (per dir, 64 WGs) ----
        if (t < TT - 1) {
            __atomic_signal_fence(__ATOMIC_SEQ_CST);
            __syncthreads();   // drains vmcnt -> sc1 stores at coherence point
            if (tid == 0) {
                __hip_atomic_fetch_add(mybar, 1u, __ATOMIC_RELAXED, __HIP_MEMORY_SCOPE_AGENT);
                unsigned tgt = (unsigned)(t + 1) * 64u;
                while (__hip_atomic_load(mybar, __ATOMIC_RELAXED, __HIP_MEMORY_SCOPE_AGENT) < tgt)
                    __builtin_amdgcn_s_sleep(2);
            }
            __syncthreads();
            __atomic_signal_fence(__ATOMIC_SEQ_CST);
        }
    }
}

// ---------------------------------------------------------------------------
// K3: feats[b][t][k] = bout[k] + [hf(b,t) | hb_rev(b,len-1-t)] . Wout[k,:]
// ---------------------------------------------------------------------------
__global__ __launch_bounds__(64) void k_feats(
    const int* __restrict__ lengths,
    const float* __restrict__ hbuf,  // [2][B][T][512]
    const float* __restrict__ Wout,  // [20][1024]
    const float* __restrict__ bout,  // [20]
    float* __restrict__ feats)       // [B][T][20]
{
    const int bt = blockIdx.x;
    const int b = bt >> 8, t = bt & 255;
    const int len = lengths[b];
    if (t >= len) return;

    __shared__ float hc[2 * HID];
    const float* hf = hbuf + ((size_t)b * TT + t) * HID;
    const float* hb = hbuf + ((size_t)(BB + b) * TT + (len - 1 - t)) * HID;
    const int tid = threadIdx.x;
    for (int i = tid; i < HID / 4; i += 64)
        ((float4*)hc)[i] = ((const float4*)hf)[i];
    for (int i = tid; i < HID / 4; i += 64)
        ((float4*)(hc + HID))[i] = ((const float4*)hb)[i];
    __syncthreads();

    if (tid < KTAGS) {
        float d = bout[tid];
        const float* wr = Wout + (size_t)tid * (2 * HID);
        #pragma unroll 4
        for (int i = 0; i < 2 * HID; i++) d = fmaf(hc[i], wr[i], d);
        feats[(size_t)bt * KTAGS + tid] = d;
    }
}

// ---------------------------------------------------------------------------
// K4: Viterbi forward + terminal + right-aligned backtrack.
// ---------------------------------------------------------------------------
__global__ __launch_bounds__(64) void k_viterbi(
    const int* __restrict__ lengths,
    const float* __restrict__ trans,  // [20][20]
    const float* __restrict__ feats,  // [B][T][20]
    int* __restrict__ bptr,           // [B][T][20]
    float* __restrict__ out)          // [32 scores][32*257 path]
{
    const int b = blockIdx.x;
    const int len = lengths[b];
    const int tid = threadIdx.x;

    __shared__ float tr[KTAGS * KTAGS];
    __shared__ float fv[KTAGS], fvn[KTAGS];

    for (int i = tid; i < KTAGS * KTAGS; i += 64) tr[i] = trans[i];
    if (tid < KTAGS) fv[tid] = (tid == START_TAG) ? 0.f : NEGV;
    __syncthreads();

    for (int t = 0; t < len; t++) {
        if (tid < KTAGS) {
            float best = -1e30f; int bi = 0;
            #pragma unroll
            for (int p = 0; p < KTAGS; p++) {
                float s = fv[p] + tr[tid * KTAGS + p];
                if (s > best) { best = s; bi = p; }
            }
            fvn[tid] = best + feats[((size_t)b * TT + t) * KTAGS + tid];
            bptr[((size_t)b * TT + t) * KTAGS + tid] = bi;
        }
        __syncthreads();
        if (tid < KTAGS) fv[tid] = fvn[tid];
        __syncthreads();
    }

    if (tid < KTAGS) fvn[tid] = fv[tid] + tr[END_TAG * KTAGS + tid];
    __syncthreads();

    if (tid == 0) {
        int bt_ = 0; float best = fvn[0];
        for (int k = 1; k < KTAGS; k++)
            if (fvn[k] > best) { best = fvn[k]; bt_ = k; }
        out[b] = best;
        float* path = out + BB + (size_t)b * (TT + 1);
        path[TT] = (float)bt_;
        int cur = bt_;
        for (int t = TT - 1; t >= 0; t--) {
            int src = t - (TT - len);
            if (src >= 0) cur = bptr[((size_t)b * TT + src) * KTAGS + cur];
            else          cur = KTAGS;
            path[t] = (float)cur;
        }
    }
}

// ---------------------------------------------------------------------------
extern "C" void kernel_launch(void* const* d_in, const int* in_sizes, int n_in,
                              void* d_out, int out_size, void* d_ws, size_t ws_size,
                              hipStream_t stream) {
    const int*   sentence = (const int*)d_in[0];
    const int*   lengths  = (const int*)d_in[1];
    const float* emb      = (const float*)d_in[2];
    const float* Wf_ih    = (const float*)d_in[3];
    const float* Wf_hh    = (const float*)d_in[4];
    const float* bf_ih    = (const float*)d_in[5];
    const float* bf_hh    = (const float*)d_in[6];
    const float* Wb_ih    = (const float*)d_in[7];
    const float* Wb_hh    = (const float*)d_in[8];
    const float* bb_ih    = (const float*)d_in[9];
    const float* bb_hh    = (const float*)d_in[10];
    const float* Wout     = (const float*)d_in[11];
    const float* bout     = (const float*)d_in[12];
    const float* trans    = (const float*)d_in[13];
    float* out = (float*)d_out;

    // workspace layout
    float*    hping = (float*)d_ws;                            // 65536 floats (256KB)
    unsigned* bar   = (unsigned*)((char*)d_ws + 65536 * 4);    // 256B region
    float*    pre   = (float*)((char*)d_ws + 65536 * 4 + 256); // 2*32*256*2048 floats
    float*    hbuf  = pre + (size_t)2 * BB * TT * G4;          // 2*32*256*512
    float*    feats = hbuf + (size_t)2 * BB * TT * HID;        // 32*256*20
    int*      bptr  = (int*)(feats + (size_t)BB * TT * KTAGS); // 32*256*20

    (void)hipMemsetAsync(d_ws, 0, 65536 * 4 + 256, stream);

    hipLaunchKernelGGL(k_pre_gemm, dim3(G4 / 64, (BB * TT) / 64, 2), dim3(256), 0, stream,
                       sentence, lengths, emb, Wf_ih, bf_ih, bf_hh, Wb_ih, bb_ih, bb_hh, pre);
    hipLaunchKernelGGL(k_lstm_persist, dim3(128), dim3(256), 0, stream,
                       lengths, Wf_hh, Wb_hh, pre, hping, bar, hbuf);
    hipLaunchKernelGGL(k_feats, dim3(BB * TT), dim3(64), 0, stream,
                       lengths, hbuf, Wout, bout, feats);
    hipLaunchKernelGGL(k_viterbi, dim3(BB), dim3(64), 0, stream,
                       lengths, trans, feats, bptr, out);
}

// Round 6
// 3368.509 us; speedup vs baseline: 4.6444x; 1.3272x over previous
//
#include <hip/hip_runtime.h>
#include <math.h>

#define VOCAB 50000
#define EMB 256
#define HID 512
#define G4 2048   // 4*HID
#define KTAGS 20
#define START_TAG 18
#define END_TAG 19
#define BB 32
#define TT 256
#define NEGV -10000.0f
#define HSROW 644   // 640 phys floats per b + 4 skew

__device__ __forceinline__ float sigmoidf_(float x) { return 1.0f / (1.0f + expf(-x)); }

// ---------------------------------------------------------------------------
// K1: pre[dir][b][t][j] = emb[tok(b,t,dir)] . Wih[j,:] + bih[j] + bhh[j]
//     Tiles whose 64 rows are all t >= len[b] are skipped (never read).
// ---------------------------------------------------------------------------
__global__ __launch_bounds__(256) void k_pre_gemm(
    const int* __restrict__ sentence, const int* __restrict__ lengths,
    const float* __restrict__ emb,
    const float* __restrict__ Wf_ih, const float* __restrict__ bf_ih, const float* __restrict__ bf_hh,
    const float* __restrict__ Wb_ih, const float* __restrict__ bb_ih, const float* __restrict__ bb_hh,
    float* __restrict__ pre)
{
    const int m0 = blockIdx.y * 64;
    if ((m0 & 255) >= lengths[m0 >> 8]) return;   // whole tile padded -> unread

    const int dir = blockIdx.z;
    const float* W  = dir ? Wb_ih : Wf_ih;   // [2048][256]
    const float* b1 = dir ? bb_ih : bf_ih;
    const float* b2 = dir ? bb_hh : bf_hh;
    float* C = pre + (size_t)dir * BB * TT * G4;

    __shared__ float As[64][17];
    __shared__ float Bs[64][17];

    const int tid = threadIdx.x;
    const int n0 = blockIdx.x * 64;

    const int lr = tid >> 2;
    const int lq = tid & 3;

    const int m    = m0 + lr;
    const int bidx = m >> 8;
    const int trow = m & 255;
    int pos = trow;
    if (dir) {
        int len = lengths[bidx];
        pos = (trow < len) ? (len - 1 - trow) : trow;
    }
    const int tok = sentence[bidx * TT + pos];
    const float* arow = emb + (size_t)tok * EMB;
    const float* wrow = W + (size_t)(n0 + lr) * EMB;

    const int ty = tid >> 4;
    const int tx = tid & 15;

    float acc[4][4];
    #pragma unroll
    for (int i = 0; i < 4; i++)
        #pragma unroll
        for (int j = 0; j < 4; j++) acc[i][j] = 0.f;

    for (int k0 = 0; k0 < EMB; k0 += 16) {
        float4 av = *(const float4*)(arow + k0 + lq * 4);
        float4 bv = *(const float4*)(wrow + k0 + lq * 4);
        As[lr][lq * 4 + 0] = av.x; As[lr][lq * 4 + 1] = av.y;
        As[lr][lq * 4 + 2] = av.z; As[lr][lq * 4 + 3] = av.w;
        Bs[lr][lq * 4 + 0] = bv.x; Bs[lr][lq * 4 + 1] = bv.y;
        Bs[lr][lq * 4 + 2] = bv.z; Bs[lr][lq * 4 + 3] = bv.w;
        __syncthreads();
        #pragma unroll
        for (int kk = 0; kk < 16; kk++) {
            float a[4], bb_[4];
            #pragma unroll
            for (int i = 0; i < 4; i++) a[i] = As[ty * 4 + i][kk];
            #pragma unroll
            for (int j = 0; j < 4; j++) bb_[j] = Bs[tx * 4 + j][kk];
            #pragma unroll
            for (int i = 0; i < 4; i++)
                #pragma unroll
                for (int j = 0; j < 4; j++)
                    acc[i][j] = fmaf(a[i], bb_[j], acc[i][j]);
        }
        __syncthreads();
    }

    float bs[4];
    #pragma unroll
    for (int j = 0; j < 4; j++) {
        int n = n0 + tx * 4 + j;
        bs[j] = b1[n] + b2[n];
    }
    #pragma unroll
    for (int i = 0; i < 4; i++) {
        int row = m0 + ty * 4 + i;
        float* cp = C + (size_t)row * G4 + n0 + tx * 4;
        #pragma unroll
        for (int j = 0; j < 4; j++) cp[j] = acc[i][j] + bs[j];
    }
}

// ---------------------------------------------------------------------------
// K2: persistent batched LSTM, fence-free sc1 protocol.
//   Staging: 16 lane-contiguous global_load_dwordx4 sc0 sc1 in ONE asm block
//   (early-clobber outputs so results never alias address pairs), one
//   vmcnt(0) round-trip, then skewed-LDS writes.
// ---------------------------------------------------------------------------
__global__ __launch_bounds__(256, 1) void k_lstm_persist(
    const int* __restrict__ lengths,
    const float* __restrict__ Wf_hh, const float* __restrict__ Wb_hh,
    const float* __restrict__ pre,     // [2][32][256][2048]
    float* __restrict__ hping,         // [2 parity][2 dir][32][512]
    unsigned* __restrict__ bar,        // bar[0]=dir0, bar[32]=dir1
    float* __restrict__ hbuf)          // [2][32][256][512]
{
    const int wg = blockIdx.x;
    const int dir = wg >> 6;
    const int slice = wg & 63;
    const int tid = threadIdx.x;
    const int wave = tid >> 6;
    const int lane = tid & 63;
    // dot identity
    const int kg = lane >> 1;              // 0..31, k range [kg*16, kg*16+16)
    const int x  = lane & 1;               // unit parity within wave
    const int u_loc  = wave * 2 + x;       // 0..7
    const int u_glob = slice * 8 + u_loc;  // 0..511
    // gate identity
    const int gu2 = lane >> 5;             // 0..1
    const int gb  = lane & 31;             // batch
    const int gul = wave * 2 + gu2;
    const int gug = slice * 8 + gul;

    const float* Whh = dir ? Wb_hh : Wf_hh;
    float4 w[4][4];                        // [gate c][float4 j]
    #pragma unroll
    for (int c = 0; c < 4; c++) {
        const float4* wr = (const float4*)(Whh + (size_t)(c * HID + u_glob) * HID + kg * 16);
        #pragma unroll
        for (int j = 0; j < 4; j++) w[c][j] = wr[j];
    }

    __shared__ float hs[32 * HSROW];       // h[b][k] at b*644 + k + 4*(k>>4)
    __shared__ float zw[8 * 132];          // zw[u_loc][c*33 + b]
    __shared__ int lens[32];
    if (tid < 32) lens[tid] = lengths[tid];
    __syncthreads();
    const int glen = lens[gb];

    // staging constants: see address derivation in comments below
    const int kqA = lane;
    const int kqB = 64 + lane;
    const int wA = 4 * (kqA + (kqA >> 2));
    const int wB = 4 * (kqB + (kqB >> 2));
    const int rowbase = wave * 2 * HSROW;

    float c_reg = 0.f;
    const float* preD = pre + (size_t)dir * BB * TT * G4;
    float* houtD = hbuf + (size_t)dir * BB * TT * HID;
    unsigned* mybar = bar + dir * 32;

    for (int t = 0; t < TT; t++) {
        // ---- stage h(t): 16 coalesced sc1 dwordx4 loads, one vmcnt ----
        // byte off in parity/dir block = wave*4096 + lane*16 + c*16384 + o*1024
        //  -> b = c*8 + wave*2 + (o>>1), k = (o&1)*256 + lane*4
        {
            const char* srcB = (const char*)hping
                             + (size_t)((t & 1) * 2 + dir) * BB * HID * 4
                             + wave * 4096 + lane * 16;
            const char* a0 = srcB;
            const char* a1 = srcB + 16384;
            const char* a2 = srcB + 32768;
            const char* a3 = srcB + 49152;
            float4 u0, u1, u2, u3, u4, u5, u6, u7, u8, u9, u10, u11, u12, u13, u14, u15;
            asm volatile(
                "global_load_dwordx4 %0, %16, off sc0 sc1\n\t"
                "global_load_dwordx4 %1, %16, off offset:1024 sc0 sc1\n\t"
                "global_load_dwordx4 %2, %16, off offset:2048 sc0 sc1\n\t"
                "global_load_dwordx4 %3, %16, off offset:3072 sc0 sc1\n\t"
                "global_load_dwordx4 %4, %17, off sc0 sc1\n\t"
                "global_load_dwordx4 %5, %17, off offset:1024 sc0 sc1\n\t"
                "global_load_dwordx4 %6, %17, off offset:2048 sc0 sc1\n\t"
                "global_load_dwordx4 %7, %17, off offset:3072 sc0 sc1\n\t"
                "global_load_dwordx4 %8, %18, off sc0 sc1\n\t"
                "global_load_dwordx4 %9, %18, off offset:1024 sc0 sc1\n\t"
                "global_load_dwordx4 %10, %18, off offset:2048 sc0 sc1\n\t"
                "global_load_dwordx4 %11, %18, off offset:3072 sc0 sc1\n\t"
                "global_load_dwordx4 %12, %19, off sc0 sc1\n\t"
                "global_load_dwordx4 %13, %19, off offset:1024 sc0 sc1\n\t"
                "global_load_dwordx4 %14, %19, off offset:2048 sc0 sc1\n\t"
                "global_load_dwordx4 %15, %19, off offset:3072 sc0 sc1\n\t"
                "s_waitcnt vmcnt(0)"
                : "=&v"(u0), "=&v"(u1), "=&v"(u2), "=&v"(u3),
                  "=&v"(u4), "=&v"(u5), "=&v"(u6), "=&v"(u7),
                  "=&v"(u8), "=&v"(u9), "=&v"(u10), "=&v"(u11),
                  "=&v"(u12), "=&v"(u13), "=&v"(u14), "=&v"(u15)
                : "v"(a0), "v"(a1), "v"(a2), "v"(a3)
                : "memory");
            // write to skewed LDS
            {
                float* r0 = &hs[rowbase];                       // c=0, b=wave*2
                *(float4*)&r0[wA] = u0;  *(float4*)&r0[wB] = u1;
                *(float4*)&r0[HSROW + wA] = u2;  *(float4*)&r0[HSROW + wB] = u3;
                float* r1 = &hs[rowbase + 8 * HSROW];           // c=1
                *(float4*)&r1[wA] = u4;  *(float4*)&r1[wB] = u5;
                *(float4*)&r1[HSROW + wA] = u6;  *(float4*)&r1[HSROW + wB] = u7;
                float* r2 = &hs[rowbase + 16 * HSROW];          // c=2
                *(float4*)&r2[wA] = u8;  *(float4*)&r2[wB] = u9;
                *(float4*)&r2[HSROW + wA] = u10; *(float4*)&r2[HSROW + wB] = u11;
                float* r3 = &hs[rowbase + 24 * HSROW];          // c=3
                *(float4*)&r3[wA] = u12; *(float4*)&r3[wB] = u13;
                *(float4*)&r3[HSROW + wA] = u14; *(float4*)&r3[HSROW + wB] = u15;
            }
        }
        __syncthreads();

        // ---- early-issue pre-activation loads ----
        float p0 = 0.f, p1 = 0.f, p2 = 0.f, p3 = 0.f;
        if (t < glen) {
            const float* pb = preD + ((size_t)gb * TT + t) * G4 + gug;
            p0 = pb[0]; p1 = pb[HID]; p2 = pb[2 * HID]; p3 = pb[3 * HID];
        }

        // ---- dot phase ----
        for (int b = 0; b < 32; b++) {
            if (t >= lens[b]) continue;
            const float* hb = &hs[b * HSROW + kg * 20];
            float4 h0 = *(const float4*)(hb);
            float4 h1 = *(const float4*)(hb + 4);
            float4 h2 = *(const float4*)(hb + 8);
            float4 h3 = *(const float4*)(hb + 12);
            float a0 = 0.f, a1 = 0.f, a2 = 0.f, a3 = 0.f;
            a0 = fmaf(w[0][0].x, h0.x, a0); a0 = fmaf(w[0][0].y, h0.y, a0);
            a0 = fmaf(w[0][0].z, h0.z, a0); a0 = fmaf(w[0][0].w, h0.w, a0);
            a0 = fmaf(w[0][1].x, h1.x, a0); a0 = fmaf(w[0][1].y, h1.y, a0);
            a0 = fmaf(w[0][1].z, h1.z, a0); a0 = fmaf(w[0][1].w, h1.w, a0);
            a0 = fmaf(w[0][2].x, h2.x, a0); a0 = fmaf(w[0][2].y, h2.y, a0);
            a0 = fmaf(w[0][2].z, h2.z, a0); a0 = fmaf(w[0][2].w, h2.w, a0);
            a0 = fmaf(w[0][3].x, h3.x, a0); a0 = fmaf(w[0][3].y, h3.y, a0);
            a0 = fmaf(w[0][3].z, h3.z, a0); a0 = fmaf(w[0][3].w, h3.w, a0);

            a1 = fmaf(w[1][0].x, h0.x, a1); a1 = fmaf(w[1][0].y, h0.y, a1);
            a1 = fmaf(w[1][0].z, h0.z, a1); a1 = fmaf(w[1][0].w, h0.w, a1);
            a1 = fmaf(w[1][1].x, h1.x, a1); a1 = fmaf(w[1][1].y, h1.y, a1);
            a1 = fmaf(w[1][1].z, h1.z, a1); a1 = fmaf(w[1][1].w, h1.w, a1);
            a1 = fmaf(w[1][2].x, h2.x, a1); a1 = fmaf(w[1][2].y, h2.y, a1);
            a1 = fmaf(w[1][2].z, h2.z, a1); a1 = fmaf(w[1][2].w, h2.w, a1);
            a1 = fmaf(w[1][3].x, h3.x, a1); a1 = fmaf(w[1][3].y, h3.y, a1);
            a1 = fmaf(w[1][3].z, h3.z, a1); a1 = fmaf(w[1][3].w, h3.w, a1);

            a2 = fmaf(w[2][0].x, h0.x, a2); a2 = fmaf(w[2][0].y, h0.y, a2);
            a2 = fmaf(w[2][0].z, h0.z, a2); a2 = fmaf(w[2][0].w, h0.w, a2);
            a2 = fmaf(w[2][1].x, h1.x, a2); a2 = fmaf(w[2][1].y, h1.y, a2);
            a2 = fmaf(w[2][1].z, h1.z, a2); a2 = fmaf(w[2][1].w, h1.w, a2);
            a2 = fmaf(w[2][2].x, h2.x, a2); a2 = fmaf(w[2][2].y, h2.y, a2);
            a2 = fmaf(w[2][2].z, h2.z, a2); a2 = fmaf(w[2][2].w, h2.w, a2);
            a2 = fmaf(w[2][3].x, h3.x, a2); a2 = fmaf(w[2][3].y, h3.y, a2);
            a2 = fmaf(w[2][3].z, h3.z, a2); a2 = fmaf(w[2][3].w, h3.w, a2);

            a3 = fmaf(w[3][0].x, h0.x, a3); a3 = fmaf(w[3][0].y, h0.y, a3);
            a3 = fmaf(w[3][0].z, h0.z, a3); a3 = fmaf(w[3][0].w, h0.w, a3);
            a3 = fmaf(w[3][1].x, h1.x, a3); a3 = fmaf(w[3][1].y, h1.y, a3);
            a3 = fmaf(w[3][1].z, h1.z, a3); a3 = fmaf(w[3][1].w, h1.w, a3);
            a3 = fmaf(w[3][2].x, h2.x, a3); a3 = fmaf(w[3][2].y, h2.y, a3);
            a3 = fmaf(w[3][2].z, h2.z, a3); a3 = fmaf(w[3][2].w, h2.w, a3);
            a3 = fmaf(w[3][3].x, h3.x, a3); a3 = fmaf(w[3][3].y, h3.y, a3);
            a3 = fmaf(w[3][3].z, h3.z, a3); a3 = fmaf(w[3][3].w, h3.w, a3);

            // transpose-butterfly reduce over 32 kg-lanes (lane bits 5..1)
            bool lo32 = (lane & 32) == 0;
            float tA = __shfl_xor(lo32 ? a2 : a0, 32);
            float tB = __shfl_xor(lo32 ? a3 : a1, 32);
            float rA = (lo32 ? a0 : a2) + tA;   // gate 0 or 2
            float rB = (lo32 ? a1 : a3) + tB;   // gate 1 or 3
            bool lo16 = (lane & 16) == 0;
            float tC = __shfl_xor(lo16 ? rB : rA, 16);
            float r  = (lo16 ? rA : rB) + tC;   // gate (lane>>4)&3
            r += __shfl_xor(r, 8);
            r += __shfl_xor(r, 4);
            r += __shfl_xor(r, 2);
            if ((lane & 14) == 0)
                zw[u_loc * 132 + ((lane >> 4) & 3) * 33 + b] = r;
        }

        // ---- gate phase: lane = (gu2, gb) ----
        if (t < glen) {
            float zi = zw[gul * 132 +  0 + gb];
            float zf = zw[gul * 132 + 33 + gb];
            float zg = zw[gul * 132 + 66 + gb];
            float zo = zw[gul * 132 + 99 + gb];
            float iv = zi + p0, fv = zf + p1, gv = zg + p2, ov = zo + p3;
            float cn = sigmoidf_(fv) * c_reg + sigmoidf_(iv) * tanhf(gv);
            float hn = sigmoidf_(ov) * tanhf(cn);
            c_reg = cn;
            houtD[((size_t)gb * TT + t) * HID + gug] = hn;
            __hip_atomic_store(
                hping + ((size_t)(((t + 1) & 1) * 2 + dir) * BB + gb) * HID + gug,
                hn, __ATOMIC_RELAXED, __HIP_MEMORY_SCOPE_AGENT);
        }

        // ---- fence-free grid barrier (per dir, 64 WGs) ----
        if (t < TT - 1) {
            __atomic_signal_fence(__ATOMIC_SEQ_CST);
            __syncthreads();   // drains vmcnt -> sc1 stores at coherence point
            if (tid == 0) {
                __hip_atomic_fetch_add(mybar, 1u, __ATOMIC_RELAXED, __HIP_MEMORY_SCOPE_AGENT);
                unsigned tgt = (unsigned)(t + 1) * 64u;
                while (__hip_atomic_load(mybar, __ATOMIC_RELAXED, __HIP_MEMORY_SCOPE_AGENT) < tgt)
                    __builtin_amdgcn_s_sleep(2);
            }
            __syncthreads();
            __atomic_signal_fence(__ATOMIC_SEQ_CST);
        }
    }
}

// ---------------------------------------------------------------------------
// K3: feats[b][t][k] = bout[k] + [hf(b,t) | hb_rev(b,len-1-t)] . Wout[k,:]
// ---------------------------------------------------------------------------
__global__ __launch_bounds__(64) void k_feats(
    const int* __restrict__ lengths,
    const float* __restrict__ hbuf,  // [2][B][T][512]
    const float* __restrict__ Wout,  // [20][1024]
    const float* __restrict__ bout,  // [20]
    float* __restrict__ feats)       // [B][T][20]
{
    const int bt = blockIdx.x;
    const int b = bt >> 8, t = bt & 255;
    const int len = lengths[b];
    if (t >= len) return;

    __shared__ float hc[2 * HID];
    const float* hf = hbuf + ((size_t)b * TT + t) * HID;
    const float* hb = hbuf + ((size_t)(BB + b) * TT + (len - 1 - t)) * HID;
    const int tid = threadIdx.x;
    for (int i = tid; i < HID / 4; i += 64)
        ((float4*)hc)[i] = ((const float4*)hf)[i];
    for (int i = tid; i < HID / 4; i += 64)
        ((float4*)(hc + HID))[i] = ((const float4*)hb)[i];
    __syncthreads();

    if (tid < KTAGS) {
        float d = bout[tid];
        const float* wr = Wout + (size_t)tid * (2 * HID);
        #pragma unroll 4
        for (int i = 0; i < 2 * HID; i++) d = fmaf(hc[i], wr[i], d);
        feats[(size_t)bt * KTAGS + tid] = d;
    }
}

// ---------------------------------------------------------------------------
// K4: Viterbi forward + terminal + right-aligned backtrack.
// ---------------------------------------------------------------------------
__global__ __launch_bounds__(64) void k_viterbi(
    const int* __restrict__ lengths,
    const float* __restrict__ trans,  // [20][20]
    const float* __restrict__ feats,  // [B][T][20]
    int* __restrict__ bptr,           // [B][T][20]
    float* __restrict__ out)          // [32 scores][32*257 path]
{
    const int b = blockIdx.x;
    const int len = lengths[b];
    const int tid = threadIdx.x;

    __shared__ float tr[KTAGS * KTAGS];
    __shared__ float fv[KTAGS], fvn[KTAGS];

    for (int i = tid; i < KTAGS * KTAGS; i += 64) tr[i] = trans[i];
    if (tid < KTAGS) fv[tid] = (tid == START_TAG) ? 0.f : NEGV;
    __syncthreads();

    for (int t = 0; t < len; t++) {
        if (tid < KTAGS) {
            float best = -1e30f; int bi = 0;
            #pragma unroll
            for (int p = 0; p < KTAGS; p++) {
                float s = fv[p] + tr[tid * KTAGS + p];
                if (s > best) { best = s; bi = p; }
            }
            fvn[tid] = best + feats[((size_t)b * TT + t) * KTAGS + tid];
            bptr[((size_t)b * TT + t) * KTAGS + tid] = bi;
        }
        __syncthreads();
        if (tid < KTAGS) fv[tid] = fvn[tid];
        __syncthreads();
    }

    if (tid < KTAGS) fvn[tid] = fv[tid] + tr[END_TAG * KTAGS + tid];
    __syncthreads();

    if (tid == 0) {
        int bt_ = 0; float best = fvn[0];
        for (int k = 1; k < KTAGS; k++)
            if (fvn[k] > best) { best = fvn[k]; bt_ = k; }
        out[b] = best;
        float* path = out + BB + (size_t)b * (TT + 1);
        path[TT] = (float)bt_;
        int cur = bt_;
        for (int t = TT - 1; t >= 0; t--) {
            int src = t - (TT - len);
            if (src >= 0) cur = bptr[((size_t)b * TT + src) * KTAGS + cur];
            else          cur = KTAGS;
            path[t] = (float)cur;
        }
    }
}

// ---------------------------------------------------------------------------
extern "C" void kernel_launch(void* const* d_in, const int* in_sizes, int n_in,
                              void* d_out, int out_size, void* d_ws, size_t ws_size,
                              hipStream_t stream) {
    const int*   sentence = (const int*)d_in[0];
    const int*   lengths  = (const int*)d_in[1];
    const float* emb      = (const float*)d_in[2];
    const float* Wf_ih    = (const float*)d_in[3];
    const float* Wf_hh    = (const float*)d_in[4];
    const float* bf_ih    = (const float*)d_in[5];
    const float* bf_hh    = (const float*)d_in[6];
    const float* Wb_ih    = (const float*)d_in[7];
    const float* Wb_hh    = (const float*)d_in[8];
    const float* bb_ih    = (const float*)d_in[9];
    const float* bb_hh    = (const float*)d_in[10];
    const float* Wout     = (const float*)d_in[11];
    const float* bout     = (const float*)d_in[12];
    const float* trans    = (const float*)d_in[13];
    float* out = (float*)d_out;

    // workspace layout
    float*    hping = (float*)d_ws;                            // 65536 floats (256KB)
    unsigned* bar   = (unsigned*)((char*)d_ws + 65536 * 4);    // 256B region
    float*    pre   = (float*)((char*)d_ws + 65536 * 4 + 256); // 2*32*256*2048 floats
    float*    hbuf  = pre + (size_t)2 * BB * TT * G4;          // 2*32*256*512
    float*    feats = hbuf + (size_t)2 * BB * TT * HID;        // 32*256*20
    int*      bptr  = (int*)(feats + (size_t)BB * TT * KTAGS); // 32*256*20

    (void)hipMemsetAsync(d_ws, 0, 65536 * 4 + 256, stream);

    hipLaunchKernelGGL(k_pre_gemm, dim3(G4 / 64, (BB * TT) / 64, 2), dim3(256), 0, stream,
                       sentence, lengths, emb, Wf_ih, bf_ih, bf_hh, Wb_ih, bb_ih, bb_hh, pre);
    hipLaunchKernelGGL(k_lstm_persist, dim3(128), dim3(256), 0, stream,
                       lengths, Wf_hh, Wb_hh, pre, hping, bar, hbuf);
    hipLaunchKernelGGL(k_feats, dim3(BB * TT), dim3(64), 0, stream,
                       lengths, hbuf, Wout, bout, feats);
    hipLaunchKernelGGL(k_viterbi, dim3(BB), dim3(64), 0, stream,
                       lengths, trans, feats, bptr, out);
}

// Round 7
// 3276.923 us; speedup vs baseline: 4.7742x; 1.0279x over previous
//
#include <hip/hip_runtime.h>
#include <math.h>

#define VOCAB 50000
#define EMB 256
#define HID 512
#define G4 2048   // 4*HID
#define KTAGS 20
#define START_TAG 18
#define END_TAG 19
#define BB 32
#define TT 256
#define NEGV -10000.0f
#define HSROW 644   // 640 phys floats per b + 4 skew

__device__ __forceinline__ float sigmoidf_(float x) { return 1.0f / (1.0f + expf(-x)); }

// ---------------------------------------------------------------------------
// K1: pre[dir][b][t][j] = emb[tok(b,t,dir)] . Wih[j,:] + bih[j] + bhh[j]
//     Tiles whose 64 rows are all t >= len[b] are skipped (never read).
// ---------------------------------------------------------------------------
__global__ __launch_bounds__(256) void k_pre_gemm(
    const int* __restrict__ sentence, const int* __restrict__ lengths,
    const float* __restrict__ emb,
    const float* __restrict__ Wf_ih, const float* __restrict__ bf_ih, const float* __restrict__ bf_hh,
    const float* __restrict__ Wb_ih, const float* __restrict__ bb_ih, const float* __restrict__ bb_hh,
    float* __restrict__ pre)
{
    const int m0 = blockIdx.y * 64;
    if ((m0 & 255) >= lengths[m0 >> 8]) return;   // whole tile padded -> unread

    const int dir = blockIdx.z;
    const float* W  = dir ? Wb_ih : Wf_ih;   // [2048][256]
    const float* b1 = dir ? bb_ih : bf_ih;
    const float* b2 = dir ? bb_hh : bf_hh;
    float* C = pre + (size_t)dir * BB * TT * G4;

    __shared__ float As[64][17];
    __shared__ float Bs[64][17];

    const int tid = threadIdx.x;
    const int n0 = blockIdx.x * 64;

    const int lr = tid >> 2;
    const int lq = tid & 3;

    const int m    = m0 + lr;
    const int bidx = m >> 8;
    const int trow = m & 255;
    int pos = trow;
    if (dir) {
        int len = lengths[bidx];
        pos = (trow < len) ? (len - 1 - trow) : trow;
    }
    const int tok = sentence[bidx * TT + pos];
    const float* arow = emb + (size_t)tok * EMB;
    const float* wrow = W + (size_t)(n0 + lr) * EMB;

    const int ty = tid >> 4;
    const int tx = tid & 15;

    float acc[4][4];
    #pragma unroll
    for (int i = 0; i < 4; i++)
        #pragma unroll
        for (int j = 0; j < 4; j++) acc[i][j] = 0.f;

    for (int k0 = 0; k0 < EMB; k0 += 16) {
        float4 av = *(const float4*)(arow + k0 + lq * 4);
        float4 bv = *(const float4*)(wrow + k0 + lq * 4);
        As[lr][lq * 4 + 0] = av.x; As[lr][lq * 4 + 1] = av.y;
        As[lr][lq * 4 + 2] = av.z; As[lr][lq * 4 + 3] = av.w;
        Bs[lr][lq * 4 + 0] = bv.x; Bs[lr][lq * 4 + 1] = bv.y;
        Bs[lr][lq * 4 + 2] = bv.z; Bs[lr][lq * 4 + 3] = bv.w;
        __syncthreads();
        #pragma unroll
        for (int kk = 0; kk < 16; kk++) {
            float a[4], bb_[4];
            #pragma unroll
            for (int i = 0; i < 4; i++) a[i] = As[ty * 4 + i][kk];
            #pragma unroll
            for (int j = 0; j < 4; j++) bb_[j] = Bs[tx * 4 + j][kk];
            #pragma unroll
            for (int i = 0; i < 4; i++)
                #pragma unroll
                for (int j = 0; j < 4; j++)
                    acc[i][j] = fmaf(a[i], bb_[j], acc[i][j]);
        }
        __syncthreads();
    }

    float bs[4];
    #pragma unroll
    for (int j = 0; j < 4; j++) {
        int n = n0 + tx * 4 + j;
        bs[j] = b1[n] + b2[n];
    }
    #pragma unroll
    for (int i = 0; i < 4; i++) {
        int row = m0 + ty * 4 + i;
        float* cp = C + (size_t)row * G4 + n0 + tx * 4;
        #pragma unroll
        for (int j = 0; j < 4; j++) cp[j] = acc[i][j] + bs[j];
    }
}

// ---------------------------------------------------------------------------
// K2: persistent batched LSTM, fence-free sc1 protocol.
//   Staging: 16 per-b-predicated global_load_dwordx4 sc0 sc1 (dead b alias
//   to a shared fallback line -> MALL broadcast). Barrier: 8 counters/dir on
//   separate cachelines (8 arrivals each), wave-0 multi-lane poll + ballot.
// ---------------------------------------------------------------------------
__global__ __launch_bounds__(256, 1) void k_lstm_persist(
    const int* __restrict__ lengths,
    const float* __restrict__ Wf_hh, const float* __restrict__ Wb_hh,
    const float* __restrict__ pre,     // [2][32][256][2048]
    float* __restrict__ hping,         // [2 parity][2 dir][32][512]
    unsigned* __restrict__ bar,        // [2 dir][8 lines x 16 uints]
    float* __restrict__ hbuf)          // [2][32][256][512]
{
    const int wg = blockIdx.x;
    const int dir = wg >> 6;
    const int slice = wg & 63;
    const int tid = threadIdx.x;
    const int wave = tid >> 6;
    const int lane = tid & 63;
    // dot identity
    const int kg = lane >> 1;              // 0..31, k range [kg*16, kg*16+16)
    const int x  = lane & 1;               // unit parity within wave
    const int u_loc  = wave * 2 + x;       // 0..7
    const int u_glob = slice * 8 + u_loc;  // 0..511
    // gate identity
    const int gu2 = lane >> 5;             // 0..1
    const int gb  = lane & 31;             // batch
    const int gul = wave * 2 + gu2;
    const int gug = slice * 8 + gul;

    const float* Whh = dir ? Wb_hh : Wf_hh;
    float4 w[4][4];                        // [gate c][float4 j]
    #pragma unroll
    for (int c = 0; c < 4; c++) {
        const float4* wr = (const float4*)(Whh + (size_t)(c * HID + u_glob) * HID + kg * 16);
        #pragma unroll
        for (int j = 0; j < 4; j++) w[c][j] = wr[j];
    }

    __shared__ float hs[32 * HSROW];       // h[b][k] at b*644 + k + 4*(k>>4)
    __shared__ float zw[8 * 132];          // zw[u_loc][c*33 + b]
    __shared__ int lens[32];
    if (tid < 32) lens[tid] = lengths[tid];
    __syncthreads();
    const int glen = lens[gb];

    const int kqA = lane;
    const int kqB = 64 + lane;
    const int wA = 4 * (kqA + (kqA >> 2));
    const int wB = 4 * (kqB + (kqB >> 2));
    const int rowbase = wave * 2 * HSROW;

    float c_reg = 0.f;
    const float* preD = pre + (size_t)dir * BB * TT * G4;
    float* houtD = hbuf + (size_t)dir * BB * TT * HID;
    unsigned* mybar = bar + dir * 128;     // 8 lines x 16 uints

    for (int t = 0; t < TT; t++) {
        // ---- stage h(t): 16 predicated coalesced sc1 dwordx4 loads ----
        // load i: c=i>>2, o=i&3 -> b = c*8 + wave*2 + (o>>1), khalf = o&1
        {
            const char* hbase = (const char*)hping
                              + (size_t)((t & 1) * 2 + dir) * BB * HID * 4;
            const char* fallback = hbase + lane * 16;
            const char* a[16];
            #pragma unroll
            for (int i = 0; i < 16; i++) {
                int c = i >> 2, o = i & 3;
                int b = c * 8 + wave * 2 + (o >> 1);
                const char* p = hbase + b * 2048 + (o & 1) * 1024 + lane * 16;
                a[i] = (t < lens[b]) ? p : fallback;
            }
            float4 u0, u1, u2, u3, u4, u5, u6, u7, u8, u9, u10, u11, u12, u13, u14, u15;
            asm volatile(
                "global_load_dwordx4 %0, %16, off sc0 sc1\n\t"
                "global_load_dwordx4 %1, %17, off sc0 sc1\n\t"
                "global_load_dwordx4 %2, %18, off sc0 sc1\n\t"
                "global_load_dwordx4 %3, %19, off sc0 sc1\n\t"
                "global_load_dwordx4 %4, %20, off sc0 sc1\n\t"
                "global_load_dwordx4 %5, %21, off sc0 sc1\n\t"
                "global_load_dwordx4 %6, %22, off sc0 sc1\n\t"
                "global_load_dwordx4 %7, %23, off sc0 sc1\n\t"
                "global_load_dwordx4 %8, %24, off sc0 sc1\n\t"
                "global_load_dwordx4 %9, %25, off sc0 sc1\n\t"
                "global_load_dwordx4 %10, %26, off sc0 sc1\n\t"
                "global_load_dwordx4 %11, %27, off sc0 sc1\n\t"
                "global_load_dwordx4 %12, %28, off sc0 sc1\n\t"
                "global_load_dwordx4 %13, %29, off sc0 sc1\n\t"
                "global_load_dwordx4 %14, %30, off sc0 sc1\n\t"
                "global_load_dwordx4 %15, %31, off sc0 sc1\n\t"
                "s_waitcnt vmcnt(0)"
                : "=&v"(u0), "=&v"(u1), "=&v"(u2), "=&v"(u3),
                  "=&v"(u4), "=&v"(u5), "=&v"(u6), "=&v"(u7),
                  "=&v"(u8), "=&v"(u9), "=&v"(u10), "=&v"(u11),
                  "=&v"(u12), "=&v"(u13), "=&v"(u14), "=&v"(u15)
                : "v"(a[0]), "v"(a[1]), "v"(a[2]), "v"(a[3]),
                  "v"(a[4]), "v"(a[5]), "v"(a[6]), "v"(a[7]),
                  "v"(a[8]), "v"(a[9]), "v"(a[10]), "v"(a[11]),
                  "v"(a[12]), "v"(a[13]), "v"(a[14]), "v"(a[15])
                : "memory");
            // write to skewed LDS
            {
                float* r0 = &hs[rowbase];                       // c=0, b=wave*2
                *(float4*)&r0[wA] = u0;  *(float4*)&r0[wB] = u1;
                *(float4*)&r0[HSROW + wA] = u2;  *(float4*)&r0[HSROW + wB] = u3;
                float* r1 = &hs[rowbase + 8 * HSROW];           // c=1
                *(float4*)&r1[wA] = u4;  *(float4*)&r1[wB] = u5;
                *(float4*)&r1[HSROW + wA] = u6;  *(float4*)&r1[HSROW + wB] = u7;
                float* r2 = &hs[rowbase + 16 * HSROW];          // c=2
                *(float4*)&r2[wA] = u8;  *(float4*)&r2[wB] = u9;
                *(float4*)&r2[HSROW + wA] = u10; *(float4*)&r2[HSROW + wB] = u11;
                float* r3 = &hs[rowbase + 24 * HSROW];          // c=3
                *(float4*)&r3[wA] = u12; *(float4*)&r3[wB] = u13;
                *(float4*)&r3[HSROW + wA] = u14; *(float4*)&r3[HSROW + wB] = u15;
            }
        }
        __syncthreads();

        // ---- early-issue pre-activation loads ----
        float p0 = 0.f, p1 = 0.f, p2 = 0.f, p3 = 0.f;
        if (t < glen) {
            const float* pb = preD + ((size_t)gb * TT + t) * G4 + gug;
            p0 = pb[0]; p1 = pb[HID]; p2 = pb[2 * HID]; p3 = pb[3 * HID];
        }

        // ---- dot phase ----
        for (int b = 0; b < 32; b++) {
            if (t >= lens[b]) continue;
            const float* hb = &hs[b * HSROW + kg * 20];
            float4 h0 = *(const float4*)(hb);
            float4 h1 = *(const float4*)(hb + 4);
            float4 h2 = *(const float4*)(hb + 8);
            float4 h3 = *(const float4*)(hb + 12);
            float a0 = 0.f, a1 = 0.f, a2 = 0.f, a3 = 0.f;
            a0 = fmaf(w[0][0].x, h0.x, a0); a0 = fmaf(w[0][0].y, h0.y, a0);
            a0 = fmaf(w[0][0].z, h0.z, a0); a0 = fmaf(w[0][0].w, h0.w, a0);
            a0 = fmaf(w[0][1].x, h1.x, a0); a0 = fmaf(w[0][1].y, h1.y, a0);
            a0 = fmaf(w[0][1].z, h1.z, a0); a0 = fmaf(w[0][1].w, h1.w, a0);
            a0 = fmaf(w[0][2].x, h2.x, a0); a0 = fmaf(w[0][2].y, h2.y, a0);
            a0 = fmaf(w[0][2].z, h2.z, a0); a0 = fmaf(w[0][2].w, h2.w, a0);
            a0 = fmaf(w[0][3].x, h3.x, a0); a0 = fmaf(w[0][3].y, h3.y, a0);
            a0 = fmaf(w[0][3].z, h3.z, a0); a0 = fmaf(w[0][3].w, h3.w, a0);

            a1 = fmaf(w[1][0].x, h0.x, a1); a1 = fmaf(w[1][0].y, h0.y, a1);
            a1 = fmaf(w[1][0].z, h0.z, a1); a1 = fmaf(w[1][0].w, h0.w, a1);
            a1 = fmaf(w[1][1].x, h1.x, a1); a1 = fmaf(w[1][1].y, h1.y, a1);
            a1 = fmaf(w[1][1].z, h1.z, a1); a1 = fmaf(w[1][1].w, h1.w, a1);
            a1 = fmaf(w[1][2].x, h2.x, a1); a1 = fmaf(w[1][2].y, h2.y, a1);
            a1 = fmaf(w[1][2].z, h2.z, a1); a1 = fmaf(w[1][2].w, h2.w, a1);
            a1 = fmaf(w[1][3].x, h3.x, a1); a1 = fmaf(w[1][3].y, h3.y, a1);
            a1 = fmaf(w[1][3].z, h3.z, a1); a1 = fmaf(w[1][3].w, h3.w, a1);

            a2 = fmaf(w[2][0].x, h0.x, a2); a2 = fmaf(w[2][0].y, h0.y, a2);
            a2 = fmaf(w[2][0].z, h0.z, a2); a2 = fmaf(w[2][0].w, h0.w, a2);
            a2 = fmaf(w[2][1].x, h1.x, a2); a2 = fmaf(w[2][1].y, h1.y, a2);
            a2 = fmaf(w[2][1].z, h1.z, a2); a2 = fmaf(w[2][1].w, h1.w, a2);
            a2 = fmaf(w[2][2].x, h2.x, a2); a2 = fmaf(w[2][2].y, h2.y, a2);
            a2 = fmaf(w[2][2].z, h2.z, a2); a2 = fmaf(w[2][2].w, h2.w, a2);
            a2 = fmaf(w[2][3].x, h3.x, a2); a2 = fmaf(w[2][3].y, h3.y, a2);
            a2 = fmaf(w[2][3].z, h3.z, a2); a2 = fmaf(w[2][3].w, h3.w, a2);

            a3 = fmaf(w[3][0].x, h0.x, a3); a3 = fmaf(w[3][0].y, h0.y, a3);
            a3 = fmaf(w[3][0].z, h0.z, a3); a3 = fmaf(w[3][0].w, h0.w, a3);
            a3 = fmaf(w[3][1].x, h1.x, a3); a3 = fmaf(w[3][1].y, h1.y, a3);
            a3 = fmaf(w[3][1].z, h1.z, a3); a3 = fmaf(w[3][1].w, h1.w, a3);
            a3 = fmaf(w[3][2].x, h2.x, a3); a3 = fmaf(w[3][2].y, h2.y, a3);
            a3 = fmaf(w[3][2].z, h2.z, a3); a3 = fmaf(w[3][2].w, h2.w, a3);
            a3 = fmaf(w[3][3].x, h3.x, a3); a3 = fmaf(w[3][3].y, h3.y, a3);
            a3 = fmaf(w[3][3].z, h3.z, a3); a3 = fmaf(w[3][3].w, h3.w, a3);

            // transpose-butterfly reduce over 32 kg-lanes (lane bits 5..1)
            bool lo32 = (lane & 32) == 0;
            float tA = __shfl_xor(lo32 ? a2 : a0, 32);
            float tB = __shfl_xor(lo32 ? a3 : a1, 32);
            float rA = (lo32 ? a0 : a2) + tA;   // gate 0 or 2
            float rB = (lo32 ? a1 : a3) + tB;   // gate 1 or 3
            bool lo16 = (lane & 16) == 0;
            float tC = __shfl_xor(lo16 ? rB : rA, 16);
            float r  = (lo16 ? rA : rB) + tC;   // gate (lane>>4)&3
            r += __shfl_xor(r, 8);
            r += __shfl_xor(r, 4);
            r += __shfl_xor(r, 2);
            if ((lane & 14) == 0)
                zw[u_loc * 132 + ((lane >> 4) & 3) * 33 + b] = r;
        }

        // ---- gate phase: lane = (gu2, gb) ----
        if (t < glen) {
            float zi = zw[gul * 132 +  0 + gb];
            float zf = zw[gul * 132 + 33 + gb];
            float zg = zw[gul * 132 + 66 + gb];
            float zo = zw[gul * 132 + 99 + gb];
            float iv = zi + p0, fv = zf + p1, gv = zg + p2, ov = zo + p3;
            float cn = sigmoidf_(fv) * c_reg + sigmoidf_(iv) * tanhf(gv);
            float hn = sigmoidf_(ov) * tanhf(cn);
            c_reg = cn;
            houtD[((size_t)gb * TT + t) * HID + gug] = hn;
            __hip_atomic_store(
                hping + ((size_t)(((t + 1) & 1) * 2 + dir) * BB + gb) * HID + gug,
                hn, __ATOMIC_RELAXED, __HIP_MEMORY_SCOPE_AGENT);
        }

        // ---- distributed grid barrier (per dir: 8 lines, 8 arrivals each) ----
        if (t < TT - 1) {
            __atomic_signal_fence(__ATOMIC_SEQ_CST);
            __syncthreads();   // drains vmcnt -> sc1 stores at coherence point
            if (tid == 0)
                __hip_atomic_fetch_add(mybar + (slice & 7) * 16, 1u,
                                       __ATOMIC_RELAXED, __HIP_MEMORY_SCOPE_AGENT);
            if (wave == 0) {
                const unsigned tgt = (unsigned)(t + 1) * 8u;
                const unsigned* cp = mybar + (lane & 7) * 16;
                bool mydone = (lane >= 8);
                while (true) {
                    if (!mydone)
                        mydone = __hip_atomic_load(cp, __ATOMIC_RELAXED,
                                                   __HIP_MEMORY_SCOPE_AGENT) >= tgt;
                    if (__ballot(mydone) == ~0ull) break;
                    __builtin_amdgcn_s_sleep(1);
                }
            }
            __syncthreads();
            __atomic_signal_fence(__ATOMIC_SEQ_CST);
        }
    }
}

// ---------------------------------------------------------------------------
// K3: feats[b][t][k] = bout[k] + [hf(b,t) | hb_rev(b,len-1-t)] . Wout[k,:]
// ---------------------------------------------------------------------------
__global__ __launch_bounds__(64) void k_feats(
    const int* __restrict__ lengths,
    const float* __restrict__ hbuf,  // [2][B][T][512]
    const float* __restrict__ Wout,  // [20][1024]
    const float* __restrict__ bout,  // [20]
    float* __restrict__ feats)       // [B][T][20]
{
    const int bt = blockIdx.x;
    const int b = bt >> 8, t = bt & 255;
    const int len = lengths[b];
    if (t >= len) return;

    __shared__ float hc[2 * HID];
    const float* hf = hbuf + ((size_t)b * TT + t) * HID;
    const float* hb = hbuf + ((size_t)(BB + b) * TT + (len - 1 - t)) * HID;
    const int tid = threadIdx.x;
    for (int i = tid; i < HID / 4; i += 64)
        ((float4*)hc)[i] = ((const float4*)hf)[i];
    for (int i = tid; i < HID / 4; i += 64)
        ((float4*)(hc + HID))[i] = ((const float4*)hb)[i];
    __syncthreads();

    if (tid < KTAGS) {
        float d = bout[tid];
        const float* wr = Wout + (size_t)tid * (2 * HID);
        #pragma unroll 4
        for (int i = 0; i < 2 * HID; i++) d = fmaf(hc[i], wr[i], d);
        feats[(size_t)bt * KTAGS + tid] = d;
    }
}

// ---------------------------------------------------------------------------
// K4: Viterbi forward + terminal + right-aligned backtrack.
// ---------------------------------------------------------------------------
__global__ __launch_bounds__(64) void k_viterbi(
    const int* __restrict__ lengths,
    const float* __restrict__ trans,  // [20][20]
    const float* __restrict__ feats,  // [B][T][20]
    int* __restrict__ bptr,           // [B][T][20]
    float* __restrict__ out)          // [32 scores][32*257 path]
{
    const int b = blockIdx.x;
    const int len = lengths[b];
    const int tid = threadIdx.x;

    __shared__ float tr[KTAGS * KTAGS];
    __shared__ float fv[KTAGS], fvn[KTAGS];

    for (int i = tid; i < KTAGS * KTAGS; i += 64) tr[i] = trans[i];
    if (tid < KTAGS) fv[tid] = (tid == START_TAG) ? 0.f : NEGV;
    __syncthreads();

    for (int t = 0; t < len; t++) {
        if (tid < KTAGS) {
            float best = -1e30f; int bi = 0;
            #pragma unroll
            for (int p = 0; p < KTAGS; p++) {
                float s = fv[p] + tr[tid * KTAGS + p];
                if (s > best) { best = s; bi = p; }
            }
            fvn[tid] = best + feats[((size_t)b * TT + t) * KTAGS + tid];
            bptr[((size_t)b * TT + t) * KTAGS + tid] = bi;
        }
        __syncthreads();
        if (tid < KTAGS) fv[tid] = fvn[tid];
        __syncthreads();
    }

    if (tid < KTAGS) fvn[tid] = fv[tid] + tr[END_TAG * KTAGS + tid];
    __syncthreads();

    if (tid == 0) {
        int bt_ = 0; float best = fvn[0];
        for (int k = 1; k < KTAGS; k++)
            if (fvn[k] > best) { best = fvn[k]; bt_ = k; }
        out[b] = best;
        float* path = out + BB + (size_t)b * (TT + 1);
        path[TT] = (float)bt_;
        int cur = bt_;
        for (int t = TT - 1; t >= 0; t--) {
            int src = t - (TT - len);
            if (src >= 0) cur = bptr[((size_t)b * TT + src) * KTAGS + cur];
            else          cur = KTAGS;
            path[t] = (float)cur;
        }
    }
}

// ---------------------------------------------------------------------------
extern "C" void kernel_launch(void* const* d_in, const int* in_sizes, int n_in,
                              void* d_out, int out_size, void* d_ws, size_t ws_size,
                              hipStream_t stream) {
    const int*   sentence = (const int*)d_in[0];
    const int*   lengths  = (const int*)d_in[1];
    const float* emb      = (const float*)d_in[2];
    const float* Wf_ih    = (const float*)d_in[3];
    const float* Wf_hh    = (const float*)d_in[4];
    const float* bf_ih    = (const float*)d_in[5];
    const float* bf_hh    = (const float*)d_in[6];
    const float* Wb_ih    = (const float*)d_in[7];
    const float* Wb_hh    = (const float*)d_in[8];
    const float* bb_ih    = (const float*)d_in[9];
    const float* bb_hh    = (const float*)d_in[10];
    const float* Wout     = (const float*)d_in[11];
    const float* bout     = (const float*)d_in[12];
    const float* trans    = (const float*)d_in[13];
    float* out = (float*)d_out;

    // workspace layout
    float*    hping = (float*)d_ws;                            // 65536 floats (256KB)
    unsigned* bar   = (unsigned*)((char*)d_ws + 65536 * 4);    // 1KB region (2x8 lines)
    float*    pre   = (float*)((char*)d_ws + 65536 * 4 + 1024);// 2*32*256*2048 floats
    float*    hbuf  = pre + (size_t)2 * BB * TT * G4;          // 2*32*256*512
    float*    feats = hbuf + (size_t)2 * BB * TT * HID;        // 32*256*20
    int*      bptr  = (int*)(feats + (size_t)BB * TT * KTAGS); // 32*256*20

    (void)hipMemsetAsync(d_ws, 0, 65536 * 4 + 1024, stream);

    hipLaunchKernelGGL(k_pre_gemm, dim3(G4 / 64, (BB * TT) / 64, 2), dim3(256), 0, stream,
                       sentence, lengths, emb, Wf_ih, bf_ih, bf_hh, Wb_ih, bb_ih, bb_hh, pre);
    hipLaunchKernelGGL(k_lstm_persist, dim3(128), dim3(256), 0, stream,
                       lengths, Wf_hh, Wb_hh, pre, hping, bar, hbuf);
    hipLaunchKernelGGL(k_feats, dim3(BB * TT), dim3(64), 0, stream,
                       lengths, hbuf, Wout, bout, feats);
    hipLaunchKernelGGL(k_viterbi, dim3(BB), dim3(64), 0, stream,
                       lengths, trans, feats, bptr, out);
}

// Round 8
// 2720.215 us; speedup vs baseline: 5.7513x; 1.2047x over previous
//
#include <hip/hip_runtime.h>
#include <math.h>

#define VOCAB 50000
#define EMB 256
#define HID 512
#define G4 2048   // 4*HID
#define KTAGS 20
#define START_TAG 18
#define END_TAG 19
#define BB 32
#define TT 256
#define NEGV -10000.0f
#define HSROW 644   // 640 phys floats per b + 4 skew

__device__ __forceinline__ float sigmoidf_(float x) { return 1.0f / (1.0f + expf(-x)); }

// ---------------------------------------------------------------------------
// K1: pre[dir][b][t][j] = emb[tok(b,t,dir)] . Wih[j,:] + bih[j] + bhh[j]
// ---------------------------------------------------------------------------
__global__ __launch_bounds__(256) void k_pre_gemm(
    const int* __restrict__ sentence, const int* __restrict__ lengths,
    const float* __restrict__ emb,
    const float* __restrict__ Wf_ih, const float* __restrict__ bf_ih, const float* __restrict__ bf_hh,
    const float* __restrict__ Wb_ih, const float* __restrict__ bb_ih, const float* __restrict__ bb_hh,
    float* __restrict__ pre)
{
    const int m0 = blockIdx.y * 64;
    if ((m0 & 255) >= lengths[m0 >> 8]) return;   // whole tile padded -> unread

    const int dir = blockIdx.z;
    const float* W  = dir ? Wb_ih : Wf_ih;   // [2048][256]
    const float* b1 = dir ? bb_ih : bf_ih;
    const float* b2 = dir ? bb_hh : bf_hh;
    float* C = pre + (size_t)dir * BB * TT * G4;

    __shared__ float As[64][17];
    __shared__ float Bs[64][17];

    const int tid = threadIdx.x;
    const int n0 = blockIdx.x * 64;

    const int lr = tid >> 2;
    const int lq = tid & 3;

    const int m    = m0 + lr;
    const int bidx = m >> 8;
    const int trow = m & 255;
    int pos = trow;
    if (dir) {
        int len = lengths[bidx];
        pos = (trow < len) ? (len - 1 - trow) : trow;
    }
    const int tok = sentence[bidx * TT + pos];
    const float* arow = emb + (size_t)tok * EMB;
    const float* wrow = W + (size_t)(n0 + lr) * EMB;

    const int ty = tid >> 4;
    const int tx = tid & 15;

    float acc[4][4];
    #pragma unroll
    for (int i = 0; i < 4; i++)
        #pragma unroll
        for (int j = 0; j < 4; j++) acc[i][j] = 0.f;

    for (int k0 = 0; k0 < EMB; k0 += 16) {
        float4 av = *(const float4*)(arow + k0 + lq * 4);
        float4 bv = *(const float4*)(wrow + k0 + lq * 4);
        As[lr][lq * 4 + 0] = av.x; As[lr][lq * 4 + 1] = av.y;
        As[lr][lq * 4 + 2] = av.z; As[lr][lq * 4 + 3] = av.w;
        Bs[lr][lq * 4 + 0] = bv.x; Bs[lr][lq * 4 + 1] = bv.y;
        Bs[lr][lq * 4 + 2] = bv.z; Bs[lr][lq * 4 + 3] = bv.w;
        __syncthreads();
        #pragma unroll
        for (int kk = 0; kk < 16; kk++) {
            float a[4], bb_[4];
            #pragma unroll
            for (int i = 0; i < 4; i++) a[i] = As[ty * 4 + i][kk];
            #pragma unroll
            for (int j = 0; j < 4; j++) bb_[j] = Bs[tx * 4 + j][kk];
            #pragma unroll
            for (int i = 0; i < 4; i++)
                #pragma unroll
                for (int j = 0; j < 4; j++)
                    acc[i][j] = fmaf(a[i], bb_[j], acc[i][j]);
        }
        __syncthreads();
    }

    float bs[4];
    #pragma unroll
    for (int j = 0; j < 4; j++) {
        int n = n0 + tx * 4 + j;
        bs[j] = b1[n] + b2[n];
    }
    #pragma unroll
    for (int i = 0; i < 4; i++) {
        int row = m0 + ty * 4 + i;
        float* cp = C + (size_t)row * G4 + n0 + tx * 4;
        #pragma unroll
        for (int j = 0; j < 4; j++) cp[j] = acc[i][j] + bs[j];
    }
}

// ---------------------------------------------------------------------------
// K2: persistent batched LSTM. 128 WGs x 512 thr (8 waves -> 2/SIMD TLP).
//   wave = hidden unit (8/WG), lane = 8-float k-slice. 32 weights/thread.
//   Batches processed in length-sorted order: dot loop j<nbt[t], no divergent
//   branch in body. Staging: 8 predicated dwordx4 sc1 loads/thread, one vmcnt.
//   Exchange via sc1 (MALL-coherent); distributed per-dir barrier.
// ---------------------------------------------------------------------------
__global__ __launch_bounds__(512, 1) void k_lstm_persist(
    const int* __restrict__ lengths,
    const float* __restrict__ Wf_hh, const float* __restrict__ Wb_hh,
    const float* __restrict__ pre,     // [2][32][256][2048]
    float* __restrict__ hping,         // [2 parity][2 dir][32][512] (raw b order)
    unsigned* __restrict__ bar,        // [2 dir][8 lines x 16 uints]
    float* __restrict__ hbuf)          // [2][32][256][512]
{
    const int wg = blockIdx.x;
    const int dir = wg >> 6;
    const int slice = wg & 63;
    const int tid = threadIdx.x;
    const int wave = tid >> 6;             // 0..7 = local unit
    const int lane = tid & 63;             // 8-float k-slice
    const int u_glob = slice * 8 + wave;   // 0..511

    const float* Whh = dir ? Wb_hh : Wf_hh;
    float4 w[4][2];                        // [gate][2 x float4] over k = lane*8..+8
    #pragma unroll
    for (int c = 0; c < 4; c++) {
        const float4* wr = (const float4*)(Whh + (size_t)(c * HID + u_glob) * HID + lane * 8);
        w[c][0] = wr[0]; w[c][1] = wr[1];
    }

    __shared__ float hs[32 * HSROW];       // sorted row j: h[order[j]][k] at k+4*(k>>4)
    __shared__ float zw[8 * 132];          // zw[wave][c*33 + j]   (wave-private)
    __shared__ int lens_raw[32];
    __shared__ int order_s[32];            // sorted pos -> raw batch
    __shared__ int lens_s[32];             // sorted lens (descending)
    __shared__ int nbt_s[TT];              // active count at step t

    if (tid < 32) lens_raw[tid] = lengths[tid];
    __syncthreads();
    if (tid < 32) {
        int me = lens_raw[tid], rank = 0;
        #pragma unroll 4
        for (int o = 0; o < 32; o++) {
            int lo = lens_raw[o];
            rank += (lo > me || (lo == me && o < tid)) ? 1 : 0;
        }
        order_s[rank] = tid;
        lens_s[rank] = me;
    }
    if (tid >= 256) {
        int t = tid - 256, c = 0;
        #pragma unroll 4
        for (int b = 0; b < 32; b++) c += (lens_raw[b] > t) ? 1 : 0;
        nbt_s[t] = c;
    }
    __syncthreads();

    // gate-phase identity: lane<32 handles (unit=wave, sorted pos j=lane)
    const int gj = lane & 31;
    const int g_act = (lane < 32);
    const int mylen = lens_s[gj];
    const int mybat = order_s[gj];
    const float* preG = pre + (size_t)dir * BB * TT * G4 + (size_t)mybat * TT * G4 + u_glob;
    float* houtG = hbuf + (size_t)dir * BB * TT * HID + (size_t)mybat * TT * HID + u_glob;
    float* hpG   = hping + (size_t)dir * BB * HID + (size_t)mybat * HID + u_glob;

    // staging identity: wave stages sorted rows 4*wave .. 4*wave+3
    int sjj[8]; int shh[8];
    #pragma unroll
    for (int i = 0; i < 8; i++) { int f = wave * 8 + i; sjj[i] = f >> 1; shh[i] = f & 1; }
    const int wbase = 4 * lane + 4 * (lane >> 2);   // LDS float offset within half-row

    // dot-phase LDS read offset
    const int rdoff = 8 * lane + 4 * (lane >> 1);

    float c_reg = 0.f;
    unsigned* mybar = bar + dir * 128;     // 8 lines x 16 uints

    for (int t = 0; t < TT; t++) {
        const int nb = nbt_s[t];
        // ---- stage h(t): 8 predicated coalesced sc1 dwordx4 loads ----
        {
            const char* hbase = (const char*)hping
                              + (size_t)((t & 1) * 2 + dir) * BB * HID * 4;
            const char* fb = hbase + lane * 16;
            const char* a[8];
            #pragma unroll
            for (int i = 0; i < 8; i++) {
                const char* p = hbase + order_s[sjj[i]] * 2048 + shh[i] * 1024 + lane * 16;
                a[i] = (sjj[i] < nb) ? p : fb;
            }
            float4 u0, u1, u2, u3, u4, u5, u6, u7;
            asm volatile(
                "global_load_dwordx4 %0, %8, off sc0 sc1\n\t"
                "global_load_dwordx4 %1, %9, off sc0 sc1\n\t"
                "global_load_dwordx4 %2, %10, off sc0 sc1\n\t"
                "global_load_dwordx4 %3, %11, off sc0 sc1\n\t"
                "global_load_dwordx4 %4, %12, off sc0 sc1\n\t"
                "global_load_dwordx4 %5, %13, off sc0 sc1\n\t"
                "global_load_dwordx4 %6, %14, off sc0 sc1\n\t"
                "global_load_dwordx4 %7, %15, off sc0 sc1\n\t"
                "s_waitcnt vmcnt(0)"
                : "=&v"(u0), "=&v"(u1), "=&v"(u2), "=&v"(u3),
                  "=&v"(u4), "=&v"(u5), "=&v"(u6), "=&v"(u7)
                : "v"(a[0]), "v"(a[1]), "v"(a[2]), "v"(a[3]),
                  "v"(a[4]), "v"(a[5]), "v"(a[6]), "v"(a[7])
                : "memory");
            *(float4*)&hs[sjj[0] * HSROW + shh[0] * 320 + wbase] = u0;
            *(float4*)&hs[sjj[1] * HSROW + shh[1] * 320 + wbase] = u1;
            *(float4*)&hs[sjj[2] * HSROW + shh[2] * 320 + wbase] = u2;
            *(float4*)&hs[sjj[3] * HSROW + shh[3] * 320 + wbase] = u3;
            *(float4*)&hs[sjj[4] * HSROW + shh[4] * 320 + wbase] = u4;
            *(float4*)&hs[sjj[5] * HSROW + shh[5] * 320 + wbase] = u5;
            *(float4*)&hs[sjj[6] * HSROW + shh[6] * 320 + wbase] = u6;
            *(float4*)&hs[sjj[7] * HSROW + shh[7] * 320 + wbase] = u7;
        }
        __syncthreads();

        // ---- early-issue pre-activation loads (gate phase operands) ----
        float p0 = 0.f, p1 = 0.f, p2 = 0.f, p3 = 0.f;
        if (g_act && t < mylen) {
            const float* pb = preG + (size_t)t * G4;
            p0 = pb[0]; p1 = pb[HID]; p2 = pb[2 * HID]; p3 = pb[3 * HID];
        }

        // ---- dot phase: uniform loop, no divergence ----
        for (int j = 0; j < nb; j++) {
            const float* hb = &hs[j * HSROW + rdoff];
            float4 h0 = *(const float4*)(hb);
            float4 h1 = *(const float4*)(hb + 4);
            float a0 = 0.f, a1 = 0.f, a2 = 0.f, a3 = 0.f;
            a0 = fmaf(w[0][0].x, h0.x, a0); a0 = fmaf(w[0][0].y, h0.y, a0);
            a0 = fmaf(w[0][0].z, h0.z, a0); a0 = fmaf(w[0][0].w, h0.w, a0);
            a0 = fmaf(w[0][1].x, h1.x, a0); a0 = fmaf(w[0][1].y, h1.y, a0);
            a0 = fmaf(w[0][1].z, h1.z, a0); a0 = fmaf(w[0][1].w, h1.w, a0);

            a1 = fmaf(w[1][0].x, h0.x, a1); a1 = fmaf(w[1][0].y, h0.y, a1);
            a1 = fmaf(w[1][0].z, h0.z, a1); a1 = fmaf(w[1][0].w, h0.w, a1);
            a1 = fmaf(w[1][1].x, h1.x, a1); a1 = fmaf(w[1][1].y, h1.y, a1);
            a1 = fmaf(w[1][1].z, h1.z, a1); a1 = fmaf(w[1][1].w, h1.w, a1);

            a2 = fmaf(w[2][0].x, h0.x, a2); a2 = fmaf(w[2][0].y, h0.y, a2);
            a2 = fmaf(w[2][0].z, h0.z, a2); a2 = fmaf(w[2][0].w, h0.w, a2);
            a2 = fmaf(w[2][1].x, h1.x, a2); a2 = fmaf(w[2][1].y, h1.y, a2);
            a2 = fmaf(w[2][1].z, h1.z, a2); a2 = fmaf(w[2][1].w, h1.w, a2);

            a3 = fmaf(w[3][0].x, h0.x, a3); a3 = fmaf(w[3][0].y, h0.y, a3);
            a3 = fmaf(w[3][0].z, h0.z, a3); a3 = fmaf(w[3][0].w, h0.w, a3);
            a3 = fmaf(w[3][1].x, h1.x, a3); a3 = fmaf(w[3][1].y, h1.y, a3);
            a3 = fmaf(w[3][1].z, h1.z, a3); a3 = fmaf(w[3][1].w, h1.w, a3);

            // transpose-butterfly: fold lane bits 5,4 into gate id, reduce 3..0
            bool lo32 = (lane & 32) == 0;
            float tA = __shfl_xor(lo32 ? a2 : a0, 32);
            float tB = __shfl_xor(lo32 ? a3 : a1, 32);
            float rA = (lo32 ? a0 : a2) + tA;   // gate 0 or 2
            float rB = (lo32 ? a1 : a3) + tB;   // gate 1 or 3
            bool lo16 = (lane & 16) == 0;
            float tC = __shfl_xor(lo16 ? rB : rA, 16);
            float r  = (lo16 ? rA : rB) + tC;   // gate (lane>>4)&3
            r += __shfl_xor(r, 8);
            r += __shfl_xor(r, 4);
            r += __shfl_xor(r, 2);
            r += __shfl_xor(r, 1);
            if ((lane & 15) == 0)
                zw[wave * 132 + (lane >> 4) * 33 + j] = r;
        }

        // ---- gate phase: wave = unit, lane = sorted pos (zw is wave-private) ----
        if (g_act && t < mylen) {
            float zi = zw[wave * 132 +  0 + gj];
            float zf = zw[wave * 132 + 33 + gj];
            float zg = zw[wave * 132 + 66 + gj];
            float zo = zw[wave * 132 + 99 + gj];
            float iv = zi + p0, fv = zf + p1, gv = zg + p2, ov = zo + p3;
            float cn = sigmoidf_(fv) * c_reg + sigmoidf_(iv) * tanhf(gv);
            float hn = sigmoidf_(ov) * tanhf(cn);
            c_reg = cn;
            houtG[(size_t)t * HID] = hn;
            __hip_atomic_store(hpG + (size_t)(((t + 1) & 1) * 2) * BB * HID,
                               hn, __ATOMIC_RELAXED, __HIP_MEMORY_SCOPE_AGENT);
        }

        // ---- distributed grid barrier (per dir: 8 lines, 8 arrivals each) ----
        if (t < TT - 1) {
            __atomic_signal_fence(__ATOMIC_SEQ_CST);
            __syncthreads();   // drains vmcnt -> sc1 stores at coherence point
            if (tid == 0)
                __hip_atomic_fetch_add(mybar + (slice & 7) * 16, 1u,
                                       __ATOMIC_RELAXED, __HIP_MEMORY_SCOPE_AGENT);
            if (wave == 0) {
                const unsigned tgt = (unsigned)(t + 1) * 8u;
                const unsigned* cp = mybar + (lane & 7) * 16;
                bool mydone = (lane >= 8);
                while (true) {
                    if (!mydone)
                        mydone = __hip_atomic_load(cp, __ATOMIC_RELAXED,
                                                   __HIP_MEMORY_SCOPE_AGENT) >= tgt;
                    if (__ballot(mydone) == ~0ull) break;
                    __builtin_amdgcn_s_sleep(1);
                }
            }
            __syncthreads();
            __atomic_signal_fence(__ATOMIC_SEQ_CST);
        }
    }
}

// ---------------------------------------------------------------------------
// K3: feats[b][t][k] = bout[k] + [hf(b,t) | hb_rev(b,len-1-t)] . Wout[k,:]
// ---------------------------------------------------------------------------
__global__ __launch_bounds__(64) void k_feats(
    const int* __restrict__ lengths,
    const float* __restrict__ hbuf,  // [2][B][T][512]
    const float* __restrict__ Wout,  // [20][1024]
    const float* __restrict__ bout,  // [20]
    float* __restrict__ feats)       // [B][T][20]
{
    const int bt = blockIdx.x;
    const int b = bt >> 8, t = bt & 255;
    const int len = lengths[b];
    if (t >= len) return;

    __shared__ float hc[2 * HID];
    const float* hf = hbuf + ((size_t)b * TT + t) * HID;
    const float* hb = hbuf + ((size_t)(BB + b) * TT + (len - 1 - t)) * HID;
    const int tid = threadIdx.x;
    for (int i = tid; i < HID / 4; i += 64)
        ((float4*)hc)[i] = ((const float4*)hf)[i];
    for (int i = tid; i < HID / 4; i += 64)
        ((float4*)(hc + HID))[i] = ((const float4*)hb)[i];
    __syncthreads();

    if (tid < KTAGS) {
        float d = bout[tid];
        const float* wr = Wout + (size_t)tid * (2 * HID);
        #pragma unroll 4
        for (int i = 0; i < 2 * HID; i++) d = fmaf(hc[i], wr[i], d);
        feats[(size_t)bt * KTAGS + tid] = d;
    }
}

// ---------------------------------------------------------------------------
// K4: Viterbi forward + terminal + right-aligned backtrack.
// ---------------------------------------------------------------------------
__global__ __launch_bounds__(64) void k_viterbi(
    const int* __restrict__ lengths,
    const float* __restrict__ trans,  // [20][20]
    const float* __restrict__ feats,  // [B][T][20]
    int* __restrict__ bptr,           // [B][T][20]
    float* __restrict__ out)          // [32 scores][32*257 path]
{
    const int b = blockIdx.x;
    const int len = lengths[b];
    const int tid = threadIdx.x;

    __shared__ float tr[KTAGS * KTAGS];
    __shared__ float fv[KTAGS], fvn[KTAGS];

    for (int i = tid; i < KTAGS * KTAGS; i += 64) tr[i] = trans[i];
    if (tid < KTAGS) fv[tid] = (tid == START_TAG) ? 0.f : NEGV;
    __syncthreads();

    for (int t = 0; t < len; t++) {
        if (tid < KTAGS) {
            float best = -1e30f; int bi = 0;
            #pragma unroll
            for (int p = 0; p < KTAGS; p++) {
                float s = fv[p] + tr[tid * KTAGS + p];
                if (s > best) { best = s; bi = p; }
            }
            fvn[tid] = best + feats[((size_t)b * TT + t) * KTAGS + tid];
            bptr[((size_t)b * TT + t) * KTAGS + tid] = bi;
        }
        __syncthreads();
        if (tid < KTAGS) fv[tid] = fvn[tid];
        __syncthreads();
    }

    if (tid < KTAGS) fvn[tid] = fv[tid] + tr[END_TAG * KTAGS + tid];
    __syncthreads();

    if (tid == 0) {
        int bt_ = 0; float best = fvn[0];
        for (int k = 1; k < KTAGS; k++)
            if (fvn[k] > best) { best = fvn[k]; bt_ = k; }
        out[b] = best;
        float* path = out + BB + (size_t)b * (TT + 1);
        path[TT] = (float)bt_;
        int cur = bt_;
        for (int t = TT - 1; t >= 0; t--) {
            int src = t - (TT - len);
            if (src >= 0) cur = bptr[((size_t)b * TT + src) * KTAGS + cur];
            else          cur = KTAGS;
            path[t] = (float)cur;
        }
    }
}

// ---------------------------------------------------------------------------
extern "C" void kernel_launch(void* const* d_in, const int* in_sizes, int n_in,
                              void* d_out, int out_size, void* d_ws, size_t ws_size,
                              hipStream_t stream) {
    const int*   sentence = (const int*)d_in[0];
    const int*   lengths  = (const int*)d_in[1];
    const float* emb      = (const float*)d_in[2];
    const float* Wf_ih    = (const float*)d_in[3];
    const float* Wf_hh    = (const float*)d_in[4];
    const float* bf_ih    = (const float*)d_in[5];
    const float* bf_hh    = (const float*)d_in[6];
    const float* Wb_ih    = (const float*)d_in[7];
    const float* Wb_hh    = (const float*)d_in[8];
    const float* bb_ih    = (const float*)d_in[9];
    const float* bb_hh    = (const float*)d_in[10];
    const float* Wout     = (const float*)d_in[11];
    const float* bout     = (const float*)d_in[12];
    const float* trans    = (const float*)d_in[13];
    float* out = (float*)d_out;

    // workspace layout
    float*    hping = (float*)d_ws;                            // 65536 floats (256KB)
    unsigned* bar   = (unsigned*)((char*)d_ws + 65536 * 4);    // 1KB region (2x8 lines)
    float*    pre   = (float*)((char*)d_ws + 65536 * 4 + 1024);// 2*32*256*2048 floats
    float*    hbuf  = pre + (size_t)2 * BB * TT * G4;          // 2*32*256*512
    float*    feats = hbuf + (size_t)2 * BB * TT * HID;        // 32*256*20
    int*      bptr  = (int*)(feats + (size_t)BB * TT * KTAGS); // 32*256*20

    (void)hipMemsetAsync(d_ws, 0, 65536 * 4 + 1024, stream);

    hipLaunchKernelGGL(k_pre_gemm, dim3(G4 / 64, (BB * TT) / 64, 2), dim3(256), 0, stream,
                       sentence, lengths, emb, Wf_ih, bf_ih, bf_hh, Wb_ih, bb_ih, bb_hh, pre);
    hipLaunchKernelGGL(k_lstm_persist, dim3(128), dim3(512), 0, stream,
                       lengths, Wf_hh, Wb_hh, pre, hping, bar, hbuf);
    hipLaunchKernelGGL(k_feats, dim3(BB * TT), dim3(64), 0, stream,
                       lengths, hbuf, Wout, bout, feats);
    hipLaunchKernelGGL(k_viterbi, dim3(BB), dim3(64), 0, stream,
                       lengths, trans, feats, bptr, out);
}

// Round 9
// 2670.426 us; speedup vs baseline: 5.8586x; 1.0186x over previous
//
#include <hip/hip_runtime.h>
#include <math.h>

#define VOCAB 50000
#define EMB 256
#define HID 512
#define G4 2048   // 4*HID
#define KTAGS 20
#define START_TAG 18
#define END_TAG 19
#define BB 32
#define TT 256
#define NEGV -10000.0f
#define HSROW 644   // 640 phys floats per row + 4 skew

__device__ __forceinline__ float sigmoidf_(float x) { return 1.0f / (1.0f + expf(-x)); }

// ---------------------------------------------------------------------------
// K1: pre[dir][b][t][j] = emb[tok(b,t,dir)] . Wih[j,:] + bih[j] + bhh[j]
// ---------------------------------------------------------------------------
__global__ __launch_bounds__(256) void k_pre_gemm(
    const int* __restrict__ sentence, const int* __restrict__ lengths,
    const float* __restrict__ emb,
    const float* __restrict__ Wf_ih, const float* __restrict__ bf_ih, const float* __restrict__ bf_hh,
    const float* __restrict__ Wb_ih, const float* __restrict__ bb_ih, const float* __restrict__ bb_hh,
    float* __restrict__ pre)
{
    const int m0 = blockIdx.y * 64;
    if ((m0 & 255) >= lengths[m0 >> 8]) return;   // whole tile padded -> unread

    const int dir = blockIdx.z;
    const float* W  = dir ? Wb_ih : Wf_ih;   // [2048][256]
    const float* b1 = dir ? bb_ih : bf_ih;
    const float* b2 = dir ? bb_hh : bf_hh;
    float* C = pre + (size_t)dir * BB * TT * G4;

    __shared__ float As[64][17];
    __shared__ float Bs[64][17];

    const int tid = threadIdx.x;
    const int n0 = blockIdx.x * 64;

    const int lr = tid >> 2;
    const int lq = tid & 3;

    const int m    = m0 + lr;
    const int bidx = m >> 8;
    const int trow = m & 255;
    int pos = trow;
    if (dir) {
        int len = lengths[bidx];
        pos = (trow < len) ? (len - 1 - trow) : trow;
    }
    const int tok = sentence[bidx * TT + pos];
    const float* arow = emb + (size_t)tok * EMB;
    const float* wrow = W + (size_t)(n0 + lr) * EMB;

    const int ty = tid >> 4;
    const int tx = tid & 15;

    float acc[4][4];
    #pragma unroll
    for (int i = 0; i < 4; i++)
        #pragma unroll
        for (int j = 0; j < 4; j++) acc[i][j] = 0.f;

    for (int k0 = 0; k0 < EMB; k0 += 16) {
        float4 av = *(const float4*)(arow + k0 + lq * 4);
        float4 bv = *(const float4*)(wrow + k0 + lq * 4);
        As[lr][lq * 4 + 0] = av.x; As[lr][lq * 4 + 1] = av.y;
        As[lr][lq * 4 + 2] = av.z; As[lr][lq * 4 + 3] = av.w;
        Bs[lr][lq * 4 + 0] = bv.x; Bs[lr][lq * 4 + 1] = bv.y;
        Bs[lr][lq * 4 + 2] = bv.z; Bs[lr][lq * 4 + 3] = bv.w;
        __syncthreads();
        #pragma unroll
        for (int kk = 0; kk < 16; kk++) {
            float a[4], bb_[4];
            #pragma unroll
            for (int i = 0; i < 4; i++) a[i] = As[ty * 4 + i][kk];
            #pragma unroll
            for (int j = 0; j < 4; j++) bb_[j] = Bs[tx * 4 + j][kk];
            #pragma unroll
            for (int i = 0; i < 4; i++)
                #pragma unroll
                for (int j = 0; j < 4; j++)
                    acc[i][j] = fmaf(a[i], bb_[j], acc[i][j]);
        }
        __syncthreads();
    }

    float bs[4];
    #pragma unroll
    for (int j = 0; j < 4; j++) {
        int n = n0 + tx * 4 + j;
        bs[j] = b1[n] + b2[n];
    }
    #pragma unroll
    for (int i = 0; i < 4; i++) {
        int row = m0 + ty * 4 + i;
        float* cp = C + (size_t)row * G4 + n0 + tx * 4;
        #pragma unroll
        for (int j = 0; j < 4; j++) cp[j] = acc[i][j] + bs[j];
    }
}

// ---------------------------------------------------------------------------
// K2: persistent batched LSTM, cohort-split.
//   512 WGs x 512 thr, 2 WGs/CU co-resident. WG = (dir, 8-unit slice,
//   8-batch sorted group). Barrier is per (dir,group) cohort: 64 WGs —
//   cohorts are fully independent (batch recurrences don't cross groups),
//   exit early at the group's max length, and co-resident WGs from other
//   cohorts hide each other's barrier stalls.
// ---------------------------------------------------------------------------
__global__ __launch_bounds__(512, 1) void k_lstm_persist(
    const int* __restrict__ lengths,
    const float* __restrict__ Wf_hh, const float* __restrict__ Wb_hh,
    const float* __restrict__ pre,     // [2][32][256][2048]
    float* __restrict__ hping,         // [2 parity][2 dir][32][512] (raw b order)
    unsigned* __restrict__ bar,        // [8 cohorts][8 lines x 16 uints]
    float* __restrict__ hbuf)          // [2][32][256][512]
{
    const int wg = blockIdx.x;             // 0..511
    const int dir = wg >> 8;
    const int slice = (wg >> 2) & 63;      // unit slice 0..63
    const int grp = wg & 3;                // sorted batch group 0..3
    const int tid = threadIdx.x;
    const int wave = tid >> 6;             // 0..7 = local unit
    const int lane = tid & 63;             // 8-float k-slice
    const int u_glob = slice * 8 + wave;   // 0..511

    const float* Whh = dir ? Wb_hh : Wf_hh;
    float4 w[4][2];                        // [gate][2 x float4] over k = lane*8..+8
    #pragma unroll
    for (int c = 0; c < 4; c++) {
        const float4* wr = (const float4*)(Whh + (size_t)(c * HID + u_glob) * HID + lane * 8);
        w[c][0] = wr[0]; w[c][1] = wr[1];
    }

    __shared__ float hs[8 * HSROW];        // local row r: h[order[grp*8+r]][k], skewed
    __shared__ float zw[8 * 132];          // zw[wave][c*33 + j]
    __shared__ int lens_raw[32];
    __shared__ int order_s[32];
    __shared__ int lens_s[32];
    __shared__ int nbt_s[TT];

    if (tid < 32) lens_raw[tid] = lengths[tid];
    __syncthreads();
    if (tid < 32) {
        int me = lens_raw[tid], rank = 0;
        #pragma unroll 4
        for (int o = 0; o < 32; o++) {
            int lo = lens_raw[o];
            rank += (lo > me || (lo == me && o < tid)) ? 1 : 0;
        }
        order_s[rank] = tid;
        lens_s[rank] = me;
    }
    if (tid >= 256) {
        int t = tid - 256, c = 0;
        #pragma unroll 4
        for (int b = 0; b < 32; b++) c += (lens_raw[b] > t) ? 1 : 0;
        nbt_s[t] = c;
    }
    __syncthreads();

    const int tlimit = lens_s[grp * 8];    // cohort max length (sorted desc)

    // gate identity: lanes 0..7 = local sorted pos within group
    const int gj = lane & 7;
    const int g_act = (lane < 8);
    const int p_sort = grp * 8 + gj;
    const int mylen = lens_s[p_sort];
    const int mybat = order_s[p_sort];
    const float* preG = pre + (size_t)dir * BB * TT * G4 + (size_t)mybat * TT * G4 + u_glob;
    float* houtG = hbuf + (size_t)dir * BB * TT * HID + (size_t)mybat * TT * HID + u_glob;
    float* hpG   = hping + (size_t)dir * BB * HID + (size_t)mybat * HID + u_glob;

    // staging identity: 2 float4 slots/thread; slot s: row r=s>>7, kq=s&127
    const int s0 = tid, s1 = tid + 512;
    const int r0 = s0 >> 7, kq0 = s0 & 127;
    const int r1 = s1 >> 7, kq1 = s1 & 127;
    const int wb0 = r0 * HSROW + 4 * kq0 + 4 * (kq0 >> 2);
    const int wb1 = r1 * HSROW + 4 * kq1 + 4 * (kq1 >> 2);
    const int sb0 = order_s[grp * 8 + r0];
    const int sb1 = order_s[grp * 8 + r1];

    // dot-phase LDS read offset
    const int rdoff = 8 * lane + 4 * (lane >> 1);

    float c_reg = 0.f;
    unsigned* mybar = bar + (dir * 4 + grp) * 128;   // cohort's 8 lines x 16 uints

    for (int t = 0; t < tlimit; t++) {
        const int nbt = nbt_s[t];
        const int jmax = min(max(nbt - grp * 8, 0), 8);

        // ---- stage h(t): 2 predicated coalesced sc1 dwordx4 loads ----
        {
            const char* hbase = (const char*)hping
                              + (size_t)((t & 1) * 2 + dir) * BB * HID * 4;
            const char* fb = hbase + (tid & 63) * 16;
            const char* a0 = (grp * 8 + r0 < nbt) ? hbase + sb0 * 2048 + kq0 * 16 : fb;
            const char* a1 = (grp * 8 + r1 < nbt) ? hbase + sb1 * 2048 + kq1 * 16 : fb;
            float4 u0, u1;
            asm volatile(
                "global_load_dwordx4 %0, %2, off sc0 sc1\n\t"
                "global_load_dwordx4 %1, %3, off sc0 sc1\n\t"
                "s_waitcnt vmcnt(0)"
                : "=&v"(u0), "=&v"(u1)
                : "v"(a0), "v"(a1)
                : "memory");
            *(float4*)&hs[wb0] = u0;
            *(float4*)&hs[wb1] = u1;
        }
        __syncthreads();

        // ---- early-issue pre-activation loads (gate operands) ----
        float p0 = 0.f, p1 = 0.f, p2 = 0.f, p3 = 0.f;
        if (g_act && t < mylen) {
            const float* pb = preG + (size_t)t * G4;
            p0 = pb[0]; p1 = pb[HID]; p2 = pb[2 * HID]; p3 = pb[3 * HID];
        }

        // ---- dot phase: uniform loop over active rows of this group ----
        for (int j = 0; j < jmax; j++) {
            const float* hb = &hs[j * HSROW + rdoff];
            float4 h0 = *(const float4*)(hb);
            float4 h1 = *(const float4*)(hb + 4);
            float a0 = 0.f, a1 = 0.f, a2 = 0.f, a3 = 0.f;
            a0 = fmaf(w[0][0].x, h0.x, a0); a0 = fmaf(w[0][0].y, h0.y, a0);
            a0 = fmaf(w[0][0].z, h0.z, a0); a0 = fmaf(w[0][0].w, h0.w, a0);
            a0 = fmaf(w[0][1].x, h1.x, a0); a0 = fmaf(w[0][1].y, h1.y, a0);
            a0 = fmaf(w[0][1].z, h1.z, a0); a0 = fmaf(w[0][1].w, h1.w, a0);

            a1 = fmaf(w[1][0].x, h0.x, a1); a1 = fmaf(w[1][0].y, h0.y, a1);
            a1 = fmaf(w[1][0].z, h0.z, a1); a1 = fmaf(w[1][0].w, h0.w, a1);
            a1 = fmaf(w[1][1].x, h1.x, a1); a1 = fmaf(w[1][1].y, h1.y, a1);
            a1 = fmaf(w[1][1].z, h1.z, a1); a1 = fmaf(w[1][1].w, h1.w, a1);

            a2 = fmaf(w[2][0].x, h0.x, a2); a2 = fmaf(w[2][0].y, h0.y, a2);
            a2 = fmaf(w[2][0].z, h0.z, a2); a2 = fmaf(w[2][0].w, h0.w, a2);
            a2 = fmaf(w[2][1].x, h1.x, a2); a2 = fmaf(w[2][1].y, h1.y, a2);
            a2 = fmaf(w[2][1].z, h1.z, a2); a2 = fmaf(w[2][1].w, h1.w, a2);

            a3 = fmaf(w[3][0].x, h0.x, a3); a3 = fmaf(w[3][0].y, h0.y, a3);
            a3 = fmaf(w[3][0].z, h0.z, a3); a3 = fmaf(w[3][0].w, h0.w, a3);
            a3 = fmaf(w[3][1].x, h1.x, a3); a3 = fmaf(w[3][1].y, h1.y, a3);
            a3 = fmaf(w[3][1].z, h1.z, a3); a3 = fmaf(w[3][1].w, h1.w, a3);

            bool lo32 = (lane & 32) == 0;
            float tA = __shfl_xor(lo32 ? a2 : a0, 32);
            float tB = __shfl_xor(lo32 ? a3 : a1, 32);
            float rA = (lo32 ? a0 : a2) + tA;
            float rB = (lo32 ? a1 : a3) + tB;
            bool lo16 = (lane & 16) == 0;
            float tC = __shfl_xor(lo16 ? rB : rA, 16);
            float r  = (lo16 ? rA : rB) + tC;
            r += __shfl_xor(r, 8);
            r += __shfl_xor(r, 4);
            r += __shfl_xor(r, 2);
            r += __shfl_xor(r, 1);
            if ((lane & 15) == 0)
                zw[wave * 132 + (lane >> 4) * 33 + j] = r;
        }

        // ---- gate phase ----
        if (g_act && t < mylen) {
            float zi = zw[wave * 132 +  0 + gj];
            float zf = zw[wave * 132 + 33 + gj];
            float zg = zw[wave * 132 + 66 + gj];
            float zo = zw[wave * 132 + 99 + gj];
            float iv = zi + p0, fv = zf + p1, gv = zg + p2, ov = zo + p3;
            float cn = sigmoidf_(fv) * c_reg + sigmoidf_(iv) * tanhf(gv);
            float hn = sigmoidf_(ov) * tanhf(cn);
            c_reg = cn;
            houtG[(size_t)t * HID] = hn;
            __hip_atomic_store(hpG + (size_t)(((t + 1) & 1) * 2) * BB * HID,
                               hn, __ATOMIC_RELAXED, __HIP_MEMORY_SCOPE_AGENT);
        }

        // ---- cohort barrier: 64 WGs, 8 lines x 8 arrivals ----
        if (t < tlimit - 1) {
            __atomic_signal_fence(__ATOMIC_SEQ_CST);
            __syncthreads();   // drains vmcnt -> sc1 stores at coherence point
            if (tid == 0)
                __hip_atomic_fetch_add(mybar + (slice & 7) * 16, 1u,
                                       __ATOMIC_RELAXED, __HIP_MEMORY_SCOPE_AGENT);
            if (wave == 0) {
                const unsigned tgt = (unsigned)(t + 1) * 8u;
                const unsigned* cp = mybar + (lane & 7) * 16;
                bool mydone = (lane >= 8);
                while (true) {
                    if (!mydone)
                        mydone = __hip_atomic_load(cp, __ATOMIC_RELAXED,
                                                   __HIP_MEMORY_SCOPE_AGENT) >= tgt;
                    if (__ballot(mydone) == ~0ull) break;
                    __builtin_amdgcn_s_sleep(1);
                }
            }
            __syncthreads();
            __atomic_signal_fence(__ATOMIC_SEQ_CST);
        }
    }
}

// ---------------------------------------------------------------------------
// K3: feats[b][t][k] = bout[k] + [hf(b,t) | hb_rev(b,len-1-t)] . Wout[k,:]
// ---------------------------------------------------------------------------
__global__ __launch_bounds__(64) void k_feats(
    const int* __restrict__ lengths,
    const float* __restrict__ hbuf,  // [2][B][T][512]
    const float* __restrict__ Wout,  // [20][1024]
    const float* __restrict__ bout,  // [20]
    float* __restrict__ feats)       // [B][T][20]
{
    const int bt = blockIdx.x;
    const int b = bt >> 8, t = bt & 255;
    const int len = lengths[b];
    if (t >= len) return;

    __shared__ float hc[2 * HID];
    const float* hf = hbuf + ((size_t)b * TT + t) * HID;
    const float* hb = hbuf + ((size_t)(BB + b) * TT + (len - 1 - t)) * HID;
    const int tid = threadIdx.x;
    for (int i = tid; i < HID / 4; i += 64)
        ((float4*)hc)[i] = ((const float4*)hf)[i];
    for (int i = tid; i < HID / 4; i += 64)
        ((float4*)(hc + HID))[i] = ((const float4*)hb)[i];
    __syncthreads();

    if (tid < KTAGS) {
        float d = bout[tid];
        const float* wr = Wout + (size_t)tid * (2 * HID);
        #pragma unroll 4
        for (int i = 0; i < 2 * HID; i++) d = fmaf(hc[i], wr[i], d);
        feats[(size_t)bt * KTAGS + tid] = d;
    }
}

// ---------------------------------------------------------------------------
// K4: Viterbi forward + terminal + right-aligned backtrack.
// ---------------------------------------------------------------------------
__global__ __launch_bounds__(64) void k_viterbi(
    const int* __restrict__ lengths,
    const float* __restrict__ trans,  // [20][20]
    const float* __restrict__ feats,  // [B][T][20]
    int* __restrict__ bptr,           // [B][T][20]
    float* __restrict__ out)          // [32 scores][32*257 path]
{
    const int b = blockIdx.x;
    const int len = lengths[b];
    const int tid = threadIdx.x;

    __shared__ float tr[KTAGS * KTAGS];
    __shared__ float fv[KTAGS], fvn[KTAGS];

    for (int i = tid; i < KTAGS * KTAGS; i += 64) tr[i] = trans[i];
    if (tid < KTAGS) fv[tid] = (tid == START_TAG) ? 0.f : NEGV;
    __syncthreads();

    for (int t = 0; t < len; t++) {
        if (tid < KTAGS) {
            float best = -1e30f; int bi = 0;
            #pragma unroll
            for (int p = 0; p < KTAGS; p++) {
                float s = fv[p] + tr[tid * KTAGS + p];
                if (s > best) { best = s; bi = p; }
            }
            fvn[tid] = best + feats[((size_t)b * TT + t) * KTAGS + tid];
            bptr[((size_t)b * TT + t) * KTAGS + tid] = bi;
        }
        __syncthreads();
        if (tid < KTAGS) fv[tid] = fvn[tid];
        __syncthreads();
    }

    if (tid < KTAGS) fvn[tid] = fv[tid] + tr[END_TAG * KTAGS + tid];
    __syncthreads();

    if (tid == 0) {
        int bt_ = 0; float best = fvn[0];
        for (int k = 1; k < KTAGS; k++)
            if (fvn[k] > best) { best = fvn[k]; bt_ = k; }
        out[b] = best;
        float* path = out + BB + (size_t)b * (TT + 1);
        path[TT] = (float)bt_;
        int cur = bt_;
        for (int t = TT - 1; t >= 0; t--) {
            int src = t - (TT - len);
            if (src >= 0) cur = bptr[((size_t)b * TT + src) * KTAGS + cur];
            else          cur = KTAGS;
            path[t] = (float)cur;
        }
    }
}

// ---------------------------------------------------------------------------
extern "C" void kernel_launch(void* const* d_in, const int* in_sizes, int n_in,
                              void* d_out, int out_size, void* d_ws, size_t ws_size,
                              hipStream_t stream) {
    const int*   sentence = (const int*)d_in[0];
    const int*   lengths  = (const int*)d_in[1];
    const float* emb      = (const float*)d_in[2];
    const float* Wf_ih    = (const float*)d_in[3];
    const float* Wf_hh    = (const float*)d_in[4];
    const float* bf_ih    = (const float*)d_in[5];
    const float* bf_hh    = (const float*)d_in[6];
    const float* Wb_ih    = (const float*)d_in[7];
    const float* Wb_hh    = (const float*)d_in[8];
    const float* bb_ih    = (const float*)d_in[9];
    const float* bb_hh    = (const float*)d_in[10];
    const float* Wout     = (const float*)d_in[11];
    const float* bout     = (const float*)d_in[12];
    const float* trans    = (const float*)d_in[13];
    float* out = (float*)d_out;

    // workspace layout
    float*    hping = (float*)d_ws;                            // 65536 floats (256KB)
    unsigned* bar   = (unsigned*)((char*)d_ws + 65536 * 4);    // 4KB (8 cohorts x 8 lines)
    float*    pre   = (float*)((char*)d_ws + 65536 * 4 + 4096);// 2*32*256*2048 floats
    float*    hbuf  = pre + (size_t)2 * BB * TT * G4;          // 2*32*256*512
    float*    feats = hbuf + (size_t)2 * BB * TT * HID;        // 32*256*20
    int*      bptr  = (int*)(feats + (size_t)BB * TT * KTAGS); // 32*256*20

    (void)hipMemsetAsync(d_ws, 0, 65536 * 4 + 4096, stream);

    hipLaunchKernelGGL(k_pre_gemm, dim3(G4 / 64, (BB * TT) / 64, 2), dim3(256), 0, stream,
                       sentence, lengths, emb, Wf_ih, bf_ih, bf_hh, Wb_ih, bb_ih, bb_hh, pre);
    hipLaunchKernelGGL(k_lstm_persist, dim3(512), dim3(512), 0, stream,
                       lengths, Wf_hh, Wb_hh, pre, hping, bar, hbuf);
    hipLaunchKernelGGL(k_feats, dim3(BB * TT), dim3(64), 0, stream,
                       lengths, hbuf, Wout, bout, feats);
    hipLaunchKernelGGL(k_viterbi, dim3(BB), dim3(64), 0, stream,
                       lengths, trans, feats, bptr, out);
}

// Round 10
// 2668.764 us; speedup vs baseline: 5.8622x; 1.0006x over previous
//
#include <hip/hip_runtime.h>
#include <math.h>

#define VOCAB 50000
#define EMB 256
#define HID 512
#define G4 2048   // 4*HID
#define KTAGS 20
#define START_TAG 18
#define END_TAG 19
#define BB 32
#define TT 256
#define NEGV -10000.0f
#define HSROW 644   // 640 phys floats per row + 4 skew

__device__ __forceinline__ float sigmoidf_(float x) { return 1.0f / (1.0f + expf(-x)); }

// ---------------------------------------------------------------------------
// K1: pre[dir][b][t][j] = emb[tok(b,t,dir)] . Wih[j,:] + bih[j] + bhh[j]
// ---------------------------------------------------------------------------
__global__ __launch_bounds__(256) void k_pre_gemm(
    const int* __restrict__ sentence, const int* __restrict__ lengths,
    const float* __restrict__ emb,
    const float* __restrict__ Wf_ih, const float* __restrict__ bf_ih, const float* __restrict__ bf_hh,
    const float* __restrict__ Wb_ih, const float* __restrict__ bb_ih, const float* __restrict__ bb_hh,
    float* __restrict__ pre)
{
    const int m0 = blockIdx.y * 64;
    if ((m0 & 255) >= lengths[m0 >> 8]) return;   // whole tile padded -> unread

    const int dir = blockIdx.z;
    const float* W  = dir ? Wb_ih : Wf_ih;   // [2048][256]
    const float* b1 = dir ? bb_ih : bf_ih;
    const float* b2 = dir ? bb_hh : bf_hh;
    float* C = pre + (size_t)dir * BB * TT * G4;

    __shared__ float As[64][17];
    __shared__ float Bs[64][17];

    const int tid = threadIdx.x;
    const int n0 = blockIdx.x * 64;

    const int lr = tid >> 2;
    const int lq = tid & 3;

    const int m    = m0 + lr;
    const int bidx = m >> 8;
    const int trow = m & 255;
    int pos = trow;
    if (dir) {
        int len = lengths[bidx];
        pos = (trow < len) ? (len - 1 - trow) : trow;
    }
    const int tok = sentence[bidx * TT + pos];
    const float* arow = emb + (size_t)tok * EMB;
    const float* wrow = W + (size_t)(n0 + lr) * EMB;

    const int ty = tid >> 4;
    const int tx = tid & 15;

    float acc[4][4];
    #pragma unroll
    for (int i = 0; i < 4; i++)
        #pragma unroll
        for (int j = 0; j < 4; j++) acc[i][j] = 0.f;

    for (int k0 = 0; k0 < EMB; k0 += 16) {
        float4 av = *(const float4*)(arow + k0 + lq * 4);
        float4 bv = *(const float4*)(wrow + k0 + lq * 4);
        As[lr][lq * 4 + 0] = av.x; As[lr][lq * 4 + 1] = av.y;
        As[lr][lq * 4 + 2] = av.z; As[lr][lq * 4 + 3] = av.w;
        Bs[lr][lq * 4 + 0] = bv.x; Bs[lr][lq * 4 + 1] = bv.y;
        Bs[lr][lq * 4 + 2] = bv.z; Bs[lr][lq * 4 + 3] = bv.w;
        __syncthreads();
        #pragma unroll
        for (int kk = 0; kk < 16; kk++) {
            float a[4], bb_[4];
            #pragma unroll
            for (int i = 0; i < 4; i++) a[i] = As[ty * 4 + i][kk];
            #pragma unroll
            for (int j = 0; j < 4; j++) bb_[j] = Bs[tx * 4 + j][kk];
            #pragma unroll
            for (int i = 0; i < 4; i++)
                #pragma unroll
                for (int j = 0; j < 4; j++)
                    acc[i][j] = fmaf(a[i], bb_[j], acc[i][j]);
        }
        __syncthreads();
    }

    float bs[4];
    #pragma unroll
    for (int j = 0; j < 4; j++) {
        int n = n0 + tx * 4 + j;
        bs[j] = b1[n] + b2[n];
    }
    #pragma unroll
    for (int i = 0; i < 4; i++) {
        int row = m0 + ty * 4 + i;
        float* cp = C + (size_t)row * G4 + n0 + tx * 4;
        #pragma unroll
        for (int j = 0; j < 4; j++) cp[j] = acc[i][j] + bs[j];
    }
}

// ---------------------------------------------------------------------------
// K2: persistent batched LSTM, dual-direction interleaved.
//   256 WGs x 512 thr (~1 WG/CU). WG = (8-unit slice, 8-batch sorted group),
//   processing BOTH directions: F.wait/stage/dot/gate/arrive then B.* per
//   step. Each cohort barrier's completion overlaps the other direction's
//   ~2us of compute, so the MALL rendezvous latency is hidden instead of
//   exposed. Weights for both dirs in VGPRs (64 regs); hs/zw LDS reused
//   across phases (hazards separated by syncthreads).
// ---------------------------------------------------------------------------
__global__ __launch_bounds__(512, 1) void k_lstm_persist(
    const int* __restrict__ lengths,
    const float* __restrict__ Wf_hh, const float* __restrict__ Wb_hh,
    const float* __restrict__ pre,     // [2][32][256][2048]
    float* __restrict__ hping,         // [2 parity][2 dir][32][512] (raw b order)
    unsigned* __restrict__ bar,        // [8 cohorts][8 lines x 16 uints]
    float* __restrict__ hbuf)          // [2][32][256][512]
{
    const int wg = blockIdx.x;             // 0..255
    const int slice = wg >> 2;             // unit slice 0..63
    const int grp = wg & 3;                // sorted batch group 0..3
    const int tid = threadIdx.x;
    const int wave = tid >> 6;             // 0..7 = local unit
    const int lane = tid & 63;             // 8-float k-slice
    const int u_glob = slice * 8 + wave;   // 0..511

    float4 wF[4][2], wB[4][2];
    #pragma unroll
    for (int c = 0; c < 4; c++) {
        const float4* wr = (const float4*)(Wf_hh + (size_t)(c * HID + u_glob) * HID + lane * 8);
        wF[c][0] = wr[0]; wF[c][1] = wr[1];
        const float4* wr2 = (const float4*)(Wb_hh + (size_t)(c * HID + u_glob) * HID + lane * 8);
        wB[c][0] = wr2[0]; wB[c][1] = wr2[1];
    }

    __shared__ float hs[8 * HSROW];        // reused F then B each step
    __shared__ float zw[8 * 132];          // wave-private, reused F then B
    __shared__ int lens_raw[32];
    __shared__ int order_s[32];
    __shared__ int lens_s[32];
    __shared__ int nbt_s[TT];

    if (tid < 32) lens_raw[tid] = lengths[tid];
    __syncthreads();
    if (tid < 32) {
        int me = lens_raw[tid], rank = 0;
        #pragma unroll 4
        for (int o = 0; o < 32; o++) {
            int lo = lens_raw[o];
            rank += (lo > me || (lo == me && o < tid)) ? 1 : 0;
        }
        order_s[rank] = tid;
        lens_s[rank] = me;
    }
    if (tid >= 256) {
        int t = tid - 256, c = 0;
        #pragma unroll 4
        for (int b = 0; b < 32; b++) c += (lens_raw[b] > t) ? 1 : 0;
        nbt_s[t] = c;
    }
    __syncthreads();

    const int tlimit = lens_s[grp * 8];    // same for both dirs

    // gate identity: lanes 0..7 = local sorted pos within group
    const int gj = lane & 7;
    const int g_act = (lane < 8);
    const int p_sort = grp * 8 + gj;
    const int mylen = lens_s[p_sort];
    const int mybat = order_s[p_sort];
    const float* preF = pre + (size_t)mybat * TT * G4 + u_glob;
    const float* preBd = pre + (size_t)(BB + mybat) * TT * G4 + u_glob;
    float* houtF = hbuf + (size_t)mybat * TT * HID + u_glob;
    float* houtB = hbuf + (size_t)(BB + mybat) * TT * HID + u_glob;
    float* hpF = hping + (size_t)mybat * HID + u_glob;              // + parity*2*BB*HID
    float* hpB = hping + (size_t)(BB + mybat) * HID + u_glob;

    // staging identity: 2 float4 slots/thread; slot s: row r=s>>7, kq=s&127
    const int s0 = tid, s1 = tid + 512;
    const int r0 = s0 >> 7, kq0 = s0 & 127;
    const int r1 = s1 >> 7, kq1 = s1 & 127;
    const int wb0 = r0 * HSROW + 4 * kq0 + 4 * (kq0 >> 2);
    const int wb1 = r1 * HSROW + 4 * kq1 + 4 * (kq1 >> 2);
    const int sb0 = order_s[grp * 8 + r0];
    const int sb1 = order_s[grp * 8 + r1];

    const int rdoff = 8 * lane + 4 * (lane >> 1);

    float cF = 0.f, cB = 0.f;
    unsigned* barF = bar + grp * 128;
    unsigned* barB = bar + (4 + grp) * 128;
    const int arr_line = (slice & 7) * 16;

#define STAGE(DIRIDX)                                                          \
    {                                                                          \
        const char* hbase = (const char*)hping                                 \
                          + (size_t)((t & 1) * 2 + (DIRIDX)) * BB * HID * 4;   \
        const char* fb = hbase + (tid & 63) * 16;                              \
        const char* a0 = (grp * 8 + r0 < nbt) ? hbase + sb0 * 2048 + kq0 * 16 : fb; \
        const char* a1 = (grp * 8 + r1 < nbt) ? hbase + sb1 * 2048 + kq1 * 16 : fb; \
        float4 u0, u1;                                                         \
        asm volatile(                                                          \
            "global_load_dwordx4 %0, %2, off sc0 sc1\n\t"                      \
            "global_load_dwordx4 %1, %3, off sc0 sc1\n\t"                      \
            "s_waitcnt vmcnt(0)"                                               \
            : "=&v"(u0), "=&v"(u1) : "v"(a0), "v"(a1) : "memory");             \
        *(float4*)&hs[wb0] = u0;                                               \
        *(float4*)&hs[wb1] = u1;                                               \
    }

#define DOTRED(WREG)                                                           \
    for (int j = 0; j < jmax; j++) {                                           \
        const float* hb = &hs[j * HSROW + rdoff];                              \
        float4 h0 = *(const float4*)(hb);                                      \
        float4 h1 = *(const float4*)(hb + 4);                                  \
        float a0 = 0.f, a1 = 0.f, a2 = 0.f, a3 = 0.f;                          \
        a0 = fmaf(WREG[0][0].x, h0.x, a0); a0 = fmaf(WREG[0][0].y, h0.y, a0);  \
        a0 = fmaf(WREG[0][0].z, h0.z, a0); a0 = fmaf(WREG[0][0].w, h0.w, a0);  \
        a0 = fmaf(WREG[0][1].x, h1.x, a0); a0 = fmaf(WREG[0][1].y, h1.y, a0);  \
        a0 = fmaf(WREG[0][1].z, h1.z, a0); a0 = fmaf(WREG[0][1].w, h1.w, a0);  \
        a1 = fmaf(WREG[1][0].x, h0.x, a1); a1 = fmaf(WREG[1][0].y, h0.y, a1);  \
        a1 = fmaf(WREG[1][0].z, h0.z, a1); a1 = fmaf(WREG[1][0].w, h0.w, a1);  \
        a1 = fmaf(WREG[1][1].x, h1.x, a1); a1 = fmaf(WREG[1][1].y, h1.y, a1);  \
        a1 = fmaf(WREG[1][1].z, h1.z, a1); a1 = fmaf(WREG[1][1].w, h1.w, a1);  \
        a2 = fmaf(WREG[2][0].x, h0.x, a2); a2 = fmaf(WREG[2][0].y, h0.y, a2);  \
        a2 = fmaf(WREG[2][0].z, h0.z, a2); a2 = fmaf(WREG[2][0].w, h0.w, a2);  \
        a2 = fmaf(WREG[2][1].x, h1.x, a2); a2 = fmaf(WREG[2][1].y, h1.y, a2);  \
        a2 = fmaf(WREG[2][1].z, h1.z, a2); a2 = fmaf(WREG[2][1].w, h1.w, a2);  \
        a3 = fmaf(WREG[3][0].x, h0.x, a3); a3 = fmaf(WREG[3][0].y, h0.y, a3);  \
        a3 = fmaf(WREG[3][0].z, h0.z, a3); a3 = fmaf(WREG[3][0].w, h0.w, a3);  \
        a3 = fmaf(WREG[3][1].x, h1.x, a3); a3 = fmaf(WREG[3][1].y, h1.y, a3);  \
        a3 = fmaf(WREG[3][1].z, h1.z, a3); a3 = fmaf(WREG[3][1].w, h1.w, a3);  \
        bool lo32 = (lane & 32) == 0;                                          \
        float tA = __shfl_xor(lo32 ? a2 : a0, 32);                             \
        float tB = __shfl_xor(lo32 ? a3 : a1, 32);                             \
        float rA = (lo32 ? a0 : a2) + tA;                                      \
        float rB = (lo32 ? a1 : a3) + tB;                                      \
        bool lo16 = (lane & 16) == 0;                                          \
        float tC = __shfl_xor(lo16 ? rB : rA, 16);                             \
        float r  = (lo16 ? rA : rB) + tC;                                      \
        r += __shfl_xor(r, 8);                                                 \
        r += __shfl_xor(r, 4);                                                 \
        r += __shfl_xor(r, 2);                                                 \
        r += __shfl_xor(r, 1);                                                 \
        if ((lane & 15) == 0)                                                  \
            zw[wave * 132 + (lane >> 4) * 33 + j] = r;                         \
    }

#define BARWAIT(BARX, TGT)                                                     \
    if (wave == 0) {                                                           \
        const unsigned tgt = (TGT);                                            \
        const unsigned* cp = (BARX) + (lane & 7) * 16;                         \
        bool mydone = (lane >= 8);                                             \
        while (true) {                                                         \
            if (!mydone)                                                       \
                mydone = __hip_atomic_load(cp, __ATOMIC_RELAXED,               \
                                           __HIP_MEMORY_SCOPE_AGENT) >= tgt;   \
            if (__ballot(mydone) == ~0ull) break;                              \
            __builtin_amdgcn_s_sleep(1);                                       \
        }                                                                      \
    }

    for (int t = 0; t < tlimit; t++) {
        const int nbt = nbt_s[t];
        const int jmax = min(max(nbt - grp * 8, 0), 8);
        const int act = g_act && (t < mylen);

        // early-issue pre-activation loads for both dirs (barrier-independent)
        float pF0 = 0.f, pF1 = 0.f, pF2 = 0.f, pF3 = 0.f;
        float pB0 = 0.f, pB1 = 0.f, pB2 = 0.f, pB3 = 0.f;
        if (act) {
            const float* pf = preF + (size_t)t * G4;
            pF0 = pf[0]; pF1 = pf[HID]; pF2 = pf[2 * HID]; pF3 = pf[3 * HID];
            const float* pb = preBd + (size_t)t * G4;
            pB0 = pb[0]; pB1 = pb[HID]; pB2 = pb[2 * HID]; pB3 = pb[3 * HID];
        }

        // ================= forward phase =================
        if (t > 0) { BARWAIT(barF, (unsigned)t * 8u); }
        __syncthreads();                               // release wait
        STAGE(0);
        __syncthreads();                               // hs ready
        DOTRED(wF);
        if (act) {
            float iv = zw[wave * 132 +  0 + gj] + pF0;
            float fv = zw[wave * 132 + 33 + gj] + pF1;
            float gv = zw[wave * 132 + 66 + gj] + pF2;
            float ov = zw[wave * 132 + 99 + gj] + pF3;
            float cn = sigmoidf_(fv) * cF + sigmoidf_(iv) * tanhf(gv);
            float hn = sigmoidf_(ov) * tanhf(cn);
            cF = cn;
            houtF[(size_t)t * HID] = hn;
            __hip_atomic_store(hpF + (size_t)(((t + 1) & 1) * 2) * BB * HID,
                               hn, __ATOMIC_RELAXED, __HIP_MEMORY_SCOPE_AGENT);
        }
        __syncthreads();                               // drain F sc1 stores
        if (t < tlimit - 1 && tid == 0)
            __hip_atomic_fetch_add(barF + arr_line, 1u,
                                   __ATOMIC_RELAXED, __HIP_MEMORY_SCOPE_AGENT);

        // ================= backward phase =================
        if (t > 0) { BARWAIT(barB, (unsigned)t * 8u); }
        __syncthreads();
        STAGE(1);
        __syncthreads();
        DOTRED(wB);
        if (act) {
            float iv = zw[wave * 132 +  0 + gj] + pB0;
            float fv = zw[wave * 132 + 33 + gj] + pB1;
            float gv = zw[wave * 132 + 66 + gj] + pB2;
            float ov = zw[wave * 132 + 99 + gj] + pB3;
            float cn = sigmoidf_(fv) * cB + sigmoidf_(iv) * tanhf(gv);
            float hn = sigmoidf_(ov) * tanhf(cn);
            cB = cn;
            houtB[(size_t)t * HID] = hn;
            __hip_atomic_store(hpB + (size_t)(((t + 1) & 1) * 2) * BB * HID,
                               hn, __ATOMIC_RELAXED, __HIP_MEMORY_SCOPE_AGENT);
        }
        __syncthreads();                               // drain B sc1 stores
        if (t < tlimit - 1 && tid == 0)
            __hip_atomic_fetch_add(barB + arr_line, 1u,
                                   __ATOMIC_RELAXED, __HIP_MEMORY_SCOPE_AGENT);
    }
#undef STAGE
#undef DOTRED
#undef BARWAIT
}

// ---------------------------------------------------------------------------
// K3: feats[b][t][k] = bout[k] + [hf(b,t) | hb_rev(b,len-1-t)] . Wout[k,:]
// ---------------------------------------------------------------------------
__global__ __launch_bounds__(64) void k_feats(
    const int* __restrict__ lengths,
    const float* __restrict__ hbuf,  // [2][B][T][512]
    const float* __restrict__ Wout,  // [20][1024]
    const float* __restrict__ bout,  // [20]
    float* __restrict__ feats)       // [B][T][20]
{
    const int bt = blockIdx.x;
    const int b = bt >> 8, t = bt & 255;
    const int len = lengths[b];
    if (t >= len) return;

    __shared__ float hc[2 * HID];
    const float* hf = hbuf + ((size_t)b * TT + t) * HID;
    const float* hb = hbuf + ((size_t)(BB + b) * TT + (len - 1 - t)) * HID;
    const int tid = threadIdx.x;
    for (int i = tid; i < HID / 4; i += 64)
        ((float4*)hc)[i] = ((const float4*)hf)[i];
    for (int i = tid; i < HID / 4; i += 64)
        ((float4*)(hc + HID))[i] = ((const float4*)hb)[i];
    __syncthreads();

    if (tid < KTAGS) {
        float d = bout[tid];
        const float* wr = Wout + (size_t)tid * (2 * HID);
        #pragma unroll 4
        for (int i = 0; i < 2 * HID; i++) d = fmaf(hc[i], wr[i], d);
        feats[(size_t)bt * KTAGS + tid] = d;
    }
}

// ---------------------------------------------------------------------------
// K4: Viterbi forward + terminal + right-aligned backtrack.
// ---------------------------------------------------------------------------
__global__ __launch_bounds__(64) void k_viterbi(
    const int* __restrict__ lengths,
    const float* __restrict__ trans,  // [20][20]
    const float* __restrict__ feats,  // [B][T][20]
    int* __restrict__ bptr,           // [B][T][20]
    float* __restrict__ out)          // [32 scores][32*257 path]
{
    const int b = blockIdx.x;
    const int len = lengths[b];
    const int tid = threadIdx.x;

    __shared__ float tr[KTAGS * KTAGS];
    __shared__ float fv[KTAGS], fvn[KTAGS];

    for (int i = tid; i < KTAGS * KTAGS; i += 64) tr[i] = trans[i];
    if (tid < KTAGS) fv[tid] = (tid == START_TAG) ? 0.f : NEGV;
    __syncthreads();

    for (int t = 0; t < len; t++) {
        if (tid < KTAGS) {
            float best = -1e30f; int bi = 0;
            #pragma unroll
            for (int p = 0; p < KTAGS; p++) {
                float s = fv[p] + tr[tid * KTAGS + p];
                if (s > best) { best = s; bi = p; }
            }
            fvn[tid] = best + feats[((size_t)b * TT + t) * KTAGS + tid];
            bptr[((size_t)b * TT + t) * KTAGS + tid] = bi;
        }
        __syncthreads();
        if (tid < KTAGS) fv[tid] = fvn[tid];
        __syncthreads();
    }

    if (tid < KTAGS) fvn[tid] = fv[tid] + tr[END_TAG * KTAGS + tid];
    __syncthreads();

    if (tid == 0) {
        int bt_ = 0; float best = fvn[0];
        for (int k = 1; k < KTAGS; k++)
            if (fvn[k] > best) { best = fvn[k]; bt_ = k; }
        out[b] = best;
        float* path = out + BB + (size_t)b * (TT + 1);
        path[TT] = (float)bt_;
        int cur = bt_;
        for (int t = TT - 1; t >= 0; t--) {
            int src = t - (TT - len);
            if (src >= 0) cur = bptr[((size_t)b * TT + src) * KTAGS + cur];
            else          cur = KTAGS;
            path[t] = (float)cur;
        }
    }
}

// ---------------------------------------------------------------------------
extern "C" void kernel_launch(void* const* d_in, const int* in_sizes, int n_in,
                              void* d_out, int out_size, void* d_ws, size_t ws_size,
                              hipStream_t stream) {
    const int*   sentence = (const int*)d_in[0];
    const int*   lengths  = (const int*)d_in[1];
    const float* emb      = (const float*)d_in[2];
    const float* Wf_ih    = (const float*)d_in[3];
    const float* Wf_hh    = (const float*)d_in[4];
    const float* bf_ih    = (const float*)d_in[5];
    const float* bf_hh    = (const float*)d_in[6];
    const float* Wb_ih    = (const float*)d_in[7];
    const float* Wb_hh    = (const float*)d_in[8];
    const float* bb_ih    = (const float*)d_in[9];
    const float* bb_hh    = (const float*)d_in[10];
    const float* Wout     = (const float*)d_in[11];
    const float* bout     = (const float*)d_in[12];
    const float* trans    = (const float*)d_in[13];
    float* out = (float*)d_out;

    // workspace layout
    float*    hping = (float*)d_ws;                            // 65536 floats (256KB)
    unsigned* bar   = (unsigned*)((char*)d_ws + 65536 * 4);    // 4KB (8 cohorts x 8 lines)
    float*    pre   = (float*)((char*)d_ws + 65536 * 4 + 4096);// 2*32*256*2048 floats
    float*    hbuf  = pre + (size_t)2 * BB * TT * G4;          // 2*32*256*512
    float*    feats = hbuf + (size_t)2 * BB * TT * HID;        // 32*256*20
    int*      bptr  = (int*)(feats + (size_t)BB * TT * KTAGS); // 32*256*20

    (void)hipMemsetAsync(d_ws, 0, 65536 * 4 + 4096, stream);

    hipLaunchKernelGGL(k_pre_gemm, dim3(G4 / 64, (BB * TT) / 64, 2), dim3(256), 0, stream,
                       sentence, lengths, emb, Wf_ih, bf_ih, bf_hh, Wb_ih, bb_ih, bb_hh, pre);
    hipLaunchKernelGGL(k_lstm_persist, dim3(256), dim3(512), 0, stream,
                       lengths, Wf_hh, Wb_hh, pre, hping, bar, hbuf);
    hipLaunchKernelGGL(k_feats, dim3(BB * TT), dim3(64), 0, stream,
                       lengths, hbuf, Wout, bout, feats);
    hipLaunchKernelGGL(k_viterbi, dim3(BB), dim3(64), 0, stream,
                       lengths, trans, feats, bptr, out);
}

// Round 11
// 2567.541 us; speedup vs baseline: 6.0933x; 1.0394x over previous
//
#include <hip/hip_runtime.h>
#include <math.h>

#define VOCAB 50000
#define EMB 256
#define HID 512
#define G4 2048   // 4*HID
#define KTAGS 20
#define START_TAG 18
#define END_TAG 19
#define BB 32
#define TT 256
#define NEGV -10000.0f
#define HSROW 644   // 640 phys floats per row + 4 skew

__device__ __forceinline__ float sigmoidf_(float x) { return 1.0f / (1.0f + expf(-x)); }

// ---------------------------------------------------------------------------
// K1: pre[dir][b][t][j] = emb[tok(b,t,dir)] . Wih[j,:] + bih[j] + bhh[j]
// ---------------------------------------------------------------------------
__global__ __launch_bounds__(256) void k_pre_gemm(
    const int* __restrict__ sentence, const int* __restrict__ lengths,
    const float* __restrict__ emb,
    const float* __restrict__ Wf_ih, const float* __restrict__ bf_ih, const float* __restrict__ bf_hh,
    const float* __restrict__ Wb_ih, const float* __restrict__ bb_ih, const float* __restrict__ bb_hh,
    float* __restrict__ pre)
{
    const int m0 = blockIdx.y * 64;
    if ((m0 & 255) >= lengths[m0 >> 8]) return;   // whole tile padded -> unread

    const int dir = blockIdx.z;
    const float* W  = dir ? Wb_ih : Wf_ih;   // [2048][256]
    const float* b1 = dir ? bb_ih : bf_ih;
    const float* b2 = dir ? bb_hh : bf_hh;
    float* C = pre + (size_t)dir * BB * TT * G4;

    __shared__ float As[64][17];
    __shared__ float Bs[64][17];

    const int tid = threadIdx.x;
    const int n0 = blockIdx.x * 64;

    const int lr = tid >> 2;
    const int lq = tid & 3;

    const int m    = m0 + lr;
    const int bidx = m >> 8;
    const int trow = m & 255;
    int pos = trow;
    if (dir) {
        int len = lengths[bidx];
        pos = (trow < len) ? (len - 1 - trow) : trow;
    }
    const int tok = sentence[bidx * TT + pos];
    const float* arow = emb + (size_t)tok * EMB;
    const float* wrow = W + (size_t)(n0 + lr) * EMB;

    const int ty = tid >> 4;
    const int tx = tid & 15;

    float acc[4][4];
    #pragma unroll
    for (int i = 0; i < 4; i++)
        #pragma unroll
        for (int j = 0; j < 4; j++) acc[i][j] = 0.f;

    for (int k0 = 0; k0 < EMB; k0 += 16) {
        float4 av = *(const float4*)(arow + k0 + lq * 4);
        float4 bv = *(const float4*)(wrow + k0 + lq * 4);
        As[lr][lq * 4 + 0] = av.x; As[lr][lq * 4 + 1] = av.y;
        As[lr][lq * 4 + 2] = av.z; As[lr][lq * 4 + 3] = av.w;
        Bs[lr][lq * 4 + 0] = bv.x; Bs[lr][lq * 4 + 1] = bv.y;
        Bs[lr][lq * 4 + 2] = bv.z; Bs[lr][lq * 4 + 3] = bv.w;
        __syncthreads();
        #pragma unroll
        for (int kk = 0; kk < 16; kk++) {
            float a[4], bb_[4];
            #pragma unroll
            for (int i = 0; i < 4; i++) a[i] = As[ty * 4 + i][kk];
            #pragma unroll
            for (int j = 0; j < 4; j++) bb_[j] = Bs[tx * 4 + j][kk];
            #pragma unroll
            for (int i = 0; i < 4; i++)
                #pragma unroll
                for (int j = 0; j < 4; j++)
                    acc[i][j] = fmaf(a[i], bb_[j], acc[i][j]);
        }
        __syncthreads();
    }

    float bs[4];
    #pragma unroll
    for (int j = 0; j < 4; j++) {
        int n = n0 + tx * 4 + j;
        bs[j] = b1[n] + b2[n];
    }
    #pragma unroll
    for (int i = 0; i < 4; i++) {
        int row = m0 + ty * 4 + i;
        float* cp = C + (size_t)row * G4 + n0 + tx * 4;
        #pragma unroll
        for (int j = 0; j < 4; j++) cp[j] = acc[i][j] + bs[j];
    }
}

// ---------------------------------------------------------------------------
// K2: persistent batched LSTM, dual-direction MERGED phases.
//   256 WGs x 512 thr (1 WG/CU). WG = (8-unit slice, 8-batch sorted group),
//   both dirs per step with ONE combined barrier wait (lanes 0-7 poll F,
//   8-15 poll B), ONE staging round-trip (16 rows: 8F+8B, 4 loads/thread,
//   single vmcnt), dots+gates back-to-back, ONE drain, both arrives.
//   F and B MALL latencies share the same windows instead of serializing.
// ---------------------------------------------------------------------------
__global__ __launch_bounds__(512, 1) void k_lstm_persist(
    const int* __restrict__ lengths,
    const float* __restrict__ Wf_hh, const float* __restrict__ Wb_hh,
    const float* __restrict__ pre,     // [2][32][256][2048]
    float* __restrict__ hping,         // [2 parity][2 dir][32][512] (raw b order)
    unsigned* __restrict__ bar,        // [8 cohorts][8 lines x 16 uints]
    float* __restrict__ hbuf)          // [2][32][256][512]
{
    const int wg = blockIdx.x;             // 0..255
    const int slice = wg >> 2;             // unit slice 0..63
    const int grp = wg & 3;                // sorted batch group 0..3
    const int tid = threadIdx.x;
    const int wave = tid >> 6;             // 0..7 = local unit
    const int lane = tid & 63;             // 8-float k-slice
    const int u_glob = slice * 8 + wave;   // 0..511

    float4 wF[4][2], wB[4][2];
    #pragma unroll
    for (int c = 0; c < 4; c++) {
        const float4* wr = (const float4*)(Wf_hh + (size_t)(c * HID + u_glob) * HID + lane * 8);
        wF[c][0] = wr[0]; wF[c][1] = wr[1];
        const float4* wr2 = (const float4*)(Wb_hh + (size_t)(c * HID + u_glob) * HID + lane * 8);
        wB[c][0] = wr2[0]; wB[c][1] = wr2[1];
    }

    __shared__ float hs[16 * HSROW];       // rows 0-7: F batches, 8-15: B batches
    __shared__ float zw[16 * 132];         // [dir*8+wave][c*33 + j]
    __shared__ int lens_raw[32];
    __shared__ int order_s[32];
    __shared__ int lens_s[32];
    __shared__ int nbt_s[TT];

    if (tid < 32) lens_raw[tid] = lengths[tid];
    __syncthreads();
    if (tid < 32) {
        int me = lens_raw[tid], rank = 0;
        #pragma unroll 4
        for (int o = 0; o < 32; o++) {
            int lo = lens_raw[o];
            rank += (lo > me || (lo == me && o < tid)) ? 1 : 0;
        }
        order_s[rank] = tid;
        lens_s[rank] = me;
    }
    if (tid >= 256) {
        int t = tid - 256, c = 0;
        #pragma unroll 4
        for (int b = 0; b < 32; b++) c += (lens_raw[b] > t) ? 1 : 0;
        nbt_s[t] = c;
    }
    __syncthreads();

    const int tlimit = lens_s[grp * 8];    // same for both dirs

    // gate identity: lanes 0..7 = local sorted pos within group
    const int gj = lane & 7;
    const int g_act = (lane < 8);
    const int p_sort = grp * 8 + gj;
    const int mylen = lens_s[p_sort];
    const int mybat = order_s[p_sort];
    const float* preF = pre + (size_t)mybat * TT * G4 + u_glob;
    const float* preBd = pre + (size_t)(BB + mybat) * TT * G4 + u_glob;
    float* houtF = hbuf + (size_t)mybat * TT * HID + u_glob;
    float* houtB = hbuf + (size_t)(BB + mybat) * TT * HID + u_glob;
    float* hpF = hping + (size_t)mybat * HID + u_glob;
    float* hpB = hping + (size_t)(BB + mybat) * HID + u_glob;

    // staging: 4 slots/thread. kq = tid&127 (float4 col), base row rA = tid>>7.
    //   slot0: F row rA, slot1: F row rA+4, slot2: B row rA, slot3: B row rA+4.
    const int kq = tid & 127;
    const int rA = tid >> 7;               // 0..3
    const int wbBase = 4 * kq + 4 * (kq >> 2);
    const int sb_lo = order_s[grp * 8 + rA];
    const int sb_hi = order_s[grp * 8 + rA + 4];

    const int rdoff = 8 * lane + 4 * (lane >> 1);

    float cF = 0.f, cB = 0.f;
    unsigned* barF = bar + grp * 128;
    unsigned* barB = bar + (4 + grp) * 128;
    const int arr_line = (slice & 7) * 16;

#define DOTRED(WREG, ROWOFF, ZOFF)                                             \
    for (int j = 0; j < jmax; j++) {                                           \
        const float* hb = &hs[((ROWOFF) + j) * HSROW + rdoff];                 \
        float4 h0 = *(const float4*)(hb);                                      \
        float4 h1 = *(const float4*)(hb + 4);                                  \
        float a0 = 0.f, a1 = 0.f, a2 = 0.f, a3 = 0.f;                          \
        a0 = fmaf(WREG[0][0].x, h0.x, a0); a0 = fmaf(WREG[0][0].y, h0.y, a0);  \
        a0 = fmaf(WREG[0][0].z, h0.z, a0); a0 = fmaf(WREG[0][0].w, h0.w, a0);  \
        a0 = fmaf(WREG[0][1].x, h1.x, a0); a0 = fmaf(WREG[0][1].y, h1.y, a0);  \
        a0 = fmaf(WREG[0][1].z, h1.z, a0); a0 = fmaf(WREG[0][1].w, h1.w, a0);  \
        a1 = fmaf(WREG[1][0].x, h0.x, a1); a1 = fmaf(WREG[1][0].y, h0.y, a1);  \
        a1 = fmaf(WREG[1][0].z, h0.z, a1); a1 = fmaf(WREG[1][0].w, h0.w, a1);  \
        a1 = fmaf(WREG[1][1].x, h1.x, a1); a1 = fmaf(WREG[1][1].y, h1.y, a1);  \
        a1 = fmaf(WREG[1][1].z, h1.z, a1); a1 = fmaf(WREG[1][1].w, h1.w, a1);  \
        a2 = fmaf(WREG[2][0].x, h0.x, a2); a2 = fmaf(WREG[2][0].y, h0.y, a2);  \
        a2 = fmaf(WREG[2][0].z, h0.z, a2); a2 = fmaf(WREG[2][0].w, h0.w, a2);  \
        a2 = fmaf(WREG[2][1].x, h1.x, a2); a2 = fmaf(WREG[2][1].y, h1.y, a2);  \
        a2 = fmaf(WREG[2][1].z, h1.z, a2); a2 = fmaf(WREG[2][1].w, h1.w, a2);  \
        a3 = fmaf(WREG[3][0].x, h0.x, a3); a3 = fmaf(WREG[3][0].y, h0.y, a3);  \
        a3 = fmaf(WREG[3][0].z, h0.z, a3); a3 = fmaf(WREG[3][0].w, h0.w, a3);  \
        a3 = fmaf(WREG[3][1].x, h1.x, a3); a3 = fmaf(WREG[3][1].y, h1.y, a3);  \
        a3 = fmaf(WREG[3][1].z, h1.z, a3); a3 = fmaf(WREG[3][1].w, h1.w, a3);  \
        bool lo32 = (lane & 32) == 0;                                          \
        float tA = __shfl_xor(lo32 ? a2 : a0, 32);                             \
        float tB = __shfl_xor(lo32 ? a3 : a1, 32);                             \
        float rAq = (lo32 ? a0 : a2) + tA;                                     \
        float rBq = (lo32 ? a1 : a3) + tB;                                     \
        bool lo16 = (lane & 16) == 0;                                          \
        float tC = __shfl_xor(lo16 ? rBq : rAq, 16);                           \
        float r  = (lo16 ? rAq : rBq) + tC;                                    \
        r += __shfl_xor(r, 8);                                                 \
        r += __shfl_xor(r, 4);                                                 \
        r += __shfl_xor(r, 2);                                                 \
        r += __shfl_xor(r, 1);                                                 \
        if ((lane & 15) == 0)                                                  \
            zw[((ZOFF) + wave) * 132 + (lane >> 4) * 33 + j] = r;              \
    }

    for (int t = 0; t < tlimit; t++) {
        const int nbt = nbt_s[t];
        const int jmax = min(max(nbt - grp * 8, 0), 8);
        const int act = g_act && (t < mylen);
        const int pred_lo = (grp * 8 + rA < nbt);
        const int pred_hi = (grp * 8 + rA + 4 < nbt);

        // early-issue pre-activation loads for both dirs (barrier-independent)
        float pF0 = 0.f, pF1 = 0.f, pF2 = 0.f, pF3 = 0.f;
        float pB0 = 0.f, pB1 = 0.f, pB2 = 0.f, pB3 = 0.f;
        if (act) {
            const float* pf = preF + (size_t)t * G4;
            pF0 = pf[0]; pF1 = pf[HID]; pF2 = pf[2 * HID]; pF3 = pf[3 * HID];
            const float* pb = preBd + (size_t)t * G4;
            pB0 = pb[0]; pB1 = pb[HID]; pB2 = pb[2 * HID]; pB3 = pb[3 * HID];
        }

        // ---- combined barrier wait: F lines on lanes 0-7, B on 8-15 ----
        if (t > 0 && wave == 0) {
            const unsigned tgt = (unsigned)t * 8u;
            const unsigned* cp = (lane < 8) ? (barF + lane * 16)
                               : (lane < 16) ? (barB + (lane - 8) * 16)
                               : barF;
            bool mydone = (lane >= 16);
            while (true) {
                if (!mydone)
                    mydone = __hip_atomic_load(cp, __ATOMIC_RELAXED,
                                               __HIP_MEMORY_SCOPE_AGENT) >= tgt;
                if (__ballot(mydone) == ~0ull) break;
                __builtin_amdgcn_s_sleep(1);
            }
        }
        __syncthreads();

        // ---- stage h(t) for BOTH dirs: 4 sc1 dwordx4 loads, one vmcnt ----
        {
            const char* baseF = (const char*)hping + (size_t)((t & 1) * 2) * BB * HID * 4;
            const char* baseB = baseF + (size_t)BB * HID * 4;
            const char* fb = baseF + (tid & 63) * 16;
            const char* a0 = pred_lo ? baseF + sb_lo * 2048 + kq * 16 : fb;
            const char* a1 = pred_hi ? baseF + sb_hi * 2048 + kq * 16 : fb;
            const char* a2 = pred_lo ? baseB + sb_lo * 2048 + kq * 16 : fb;
            const char* a3 = pred_hi ? baseB + sb_hi * 2048 + kq * 16 : fb;
            float4 u0, u1, u2, u3;
            asm volatile(
                "global_load_dwordx4 %0, %4, off sc0 sc1\n\t"
                "global_load_dwordx4 %1, %5, off sc0 sc1\n\t"
                "global_load_dwordx4 %2, %6, off sc0 sc1\n\t"
                "global_load_dwordx4 %3, %7, off sc0 sc1\n\t"
                "s_waitcnt vmcnt(0)"
                : "=&v"(u0), "=&v"(u1), "=&v"(u2), "=&v"(u3)
                : "v"(a0), "v"(a1), "v"(a2), "v"(a3)
                : "memory");
            *(float4*)&hs[(rA     ) * HSROW + wbBase] = u0;
            *(float4*)&hs[(rA +  4) * HSROW + wbBase] = u1;
            *(float4*)&hs[(rA +  8) * HSROW + wbBase] = u2;
            *(float4*)&hs[(rA + 12) * HSROW + wbBase] = u3;
        }
        __syncthreads();

        // ---- dots: F then B, back-to-back ----
        DOTRED(wF, 0, 0);
        DOTRED(wB, 8, 8);

        // ---- gates: both dirs ----
        if (act) {
            {
                float iv = zw[wave * 132 +  0 + gj] + pF0;
                float fv = zw[wave * 132 + 33 + gj] + pF1;
                float gv = zw[wave * 132 + 66 + gj] + pF2;
                float ov = zw[wave * 132 + 99 + gj] + pF3;
                float cn = sigmoidf_(fv) * cF + sigmoidf_(iv) * tanhf(gv);
                float hn = sigmoidf_(ov) * tanhf(cn);
                cF = cn;
                houtF[(size_t)t * HID] = hn;
                __hip_atomic_store(hpF + (size_t)(((t + 1) & 1) * 2) * BB * HID,
                                   hn, __ATOMIC_RELAXED, __HIP_MEMORY_SCOPE_AGENT);
            }
            {
                float iv = zw[(8 + wave) * 132 +  0 + gj] + pB0;
                float fv = zw[(8 + wave) * 132 + 33 + gj] + pB1;
                float gv = zw[(8 + wave) * 132 + 66 + gj] + pB2;
                float ov = zw[(8 + wave) * 132 + 99 + gj] + pB3;
                float cn = sigmoidf_(fv) * cB + sigmoidf_(iv) * tanhf(gv);
                float hn = sigmoidf_(ov) * tanhf(cn);
                cB = cn;
                houtB[(size_t)t * HID] = hn;
                __hip_atomic_store(hpB + (size_t)(((t + 1) & 1) * 2) * BB * HID,
                                   hn, __ATOMIC_RELAXED, __HIP_MEMORY_SCOPE_AGENT);
            }
        }

        // ---- single drain + both arrives ----
        __syncthreads();   // drains all sc1 stores (vmcnt) before arrivals
        if (t < tlimit - 1) {
            if (tid == 0)
                __hip_atomic_fetch_add(barF + arr_line, 1u,
                                       __ATOMIC_RELAXED, __HIP_MEMORY_SCOPE_AGENT);
            if (tid == 1)
                __hip_atomic_fetch_add(barB + arr_line, 1u,
                                       __ATOMIC_RELAXED, __HIP_MEMORY_SCOPE_AGENT);
        }
    }
#undef DOTRED
}

// ---------------------------------------------------------------------------
// K3: feats[b][t][k] = bout[k] + [hf(b,t) | hb_rev(b,len-1-t)] . Wout[k,:]
// ---------------------------------------------------------------------------
__global__ __launch_bounds__(64) void k_feats(
    const int* __restrict__ lengths,
    const float* __restrict__ hbuf,  // [2][B][T][512]
    const float* __restrict__ Wout,  // [20][1024]
    const float* __restrict__ bout,  // [20]
    float* __restrict__ feats)       // [B][T][20]
{
    const int bt = blockIdx.x;
    const int b = bt >> 8, t = bt & 255;
    const int len = lengths[b];
    if (t >= len) return;

    __shared__ float hc[2 * HID];
    const float* hf = hbuf + ((size_t)b * TT + t) * HID;
    const float* hb = hbuf + ((size_t)(BB + b) * TT + (len - 1 - t)) * HID;
    const int tid = threadIdx.x;
    for (int i = tid; i < HID / 4; i += 64)
        ((float4*)hc)[i] = ((const float4*)hf)[i];
    for (int i = tid; i < HID / 4; i += 64)
        ((float4*)(hc + HID))[i] = ((const float4*)hb)[i];
    __syncthreads();

    if (tid < KTAGS) {
        float d = bout[tid];
        const float* wr = Wout + (size_t)tid * (2 * HID);
        #pragma unroll 4
        for (int i = 0; i < 2 * HID; i++) d = fmaf(hc[i], wr[i], d);
        feats[(size_t)bt * KTAGS + tid] = d;
    }
}

// ---------------------------------------------------------------------------
// K4: Viterbi forward + terminal + right-aligned backtrack.
// ---------------------------------------------------------------------------
__global__ __launch_bounds__(64) void k_viterbi(
    const int* __restrict__ lengths,
    const float* __restrict__ trans,  // [20][20]
    const float* __restrict__ feats,  // [B][T][20]
    int* __restrict__ bptr,           // [B][T][20]
    float* __restrict__ out)          // [32 scores][32*257 path]
{
    const int b = blockIdx.x;
    const int len = lengths[b];
    const int tid = threadIdx.x;

    __shared__ float tr[KTAGS * KTAGS];
    __shared__ float fv[KTAGS], fvn[KTAGS];

    for (int i = tid; i < KTAGS * KTAGS; i += 64) tr[i] = trans[i];
    if (tid < KTAGS) fv[tid] = (tid == START_TAG) ? 0.f : NEGV;
    __syncthreads();

    for (int t = 0; t < len; t++) {
        if (tid < KTAGS) {
            float best = -1e30f; int bi = 0;
            #pragma unroll
            for (int p = 0; p < KTAGS; p++) {
                float s = fv[p] + tr[tid * KTAGS + p];
                if (s > best) { best = s; bi = p; }
            }
            fvn[tid] = best + feats[((size_t)b * TT + t) * KTAGS + tid];
            bptr[((size_t)b * TT + t) * KTAGS + tid] = bi;
        }
        __syncthreads();
        if (tid < KTAGS) fv[tid] = fvn[tid];
        __syncthreads();
    }

    if (tid < KTAGS) fvn[tid] = fv[tid] + tr[END_TAG * KTAGS + tid];
    __syncthreads();

    if (tid == 0) {
        int bt_ = 0; float best = fvn[0];
        for (int k = 1; k < KTAGS; k++)
            if (fvn[k] > best) { best = fvn[k]; bt_ = k; }
        out[b] = best;
        float* path = out + BB + (size_t)b * (TT + 1);
        path[TT] = (float)bt_;
        int cur = bt_;
        for (int t = TT - 1; t >= 0; t--) {
            int src = t - (TT - len);
            if (src >= 0) cur = bptr[((size_t)b * TT + src) * KTAGS + cur];
            else          cur = KTAGS;
            path[t] = (float)cur;
        }
    }
}

// ---------------------------------------------------------------------------
extern "C" void kernel_launch(void* const* d_in, const int* in_sizes, int n_in,
                              void* d_out, int out_size, void* d_ws, size_t ws_size,
                              hipStream_t stream) {
    const int*   sentence = (const int*)d_in[0];
    const int*   lengths  = (const int*)d_in[1];
    const float* emb      = (const float*)d_in[2];
    const float* Wf_ih    = (const float*)d_in[3];
    const float* Wf_hh    = (const float*)d_in[4];
    const float* bf_ih    = (const float*)d_in[5];
    const float* bf_hh    = (const float*)d_in[6];
    const float* Wb_ih    = (const float*)d_in[7];
    const float* Wb_hh    = (const float*)d_in[8];
    const float* bb_ih    = (const float*)d_in[9];
    const float* bb_hh    = (const float*)d_in[10];
    const float* Wout     = (const float*)d_in[11];
    const float* bout     = (const float*)d_in[12];
    const float* trans    = (const float*)d_in[13];
    float* out = (float*)d_out;

    // workspace layout
    float*    hping = (float*)d_ws;                            // 65536 floats (256KB)
    unsigned* bar   = (unsigned*)((char*)d_ws + 65536 * 4);    // 4KB (8 cohorts x 8 lines)
    float*    pre   = (float*)((char*)d_ws + 65536 * 4 + 4096);// 2*32*256*2048 floats
    float*    hbuf  = pre + (size_t)2 * BB * TT * G4;          // 2*32*256*512
    float*    feats = hbuf + (size_t)2 * BB * TT * HID;        // 32*256*20
    int*      bptr  = (int*)(feats + (size_t)BB * TT * KTAGS); // 32*256*20

    (void)hipMemsetAsync(d_ws, 0, 65536 * 4 + 4096, stream);

    hipLaunchKernelGGL(k_pre_gemm, dim3(G4 / 64, (BB * TT) / 64, 2), dim3(256), 0, stream,
                       sentence, lengths, emb, Wf_ih, bf_ih, bf_hh, Wb_ih, bb_ih, bb_hh, pre);
    hipLaunchKernelGGL(k_lstm_persist, dim3(256), dim3(512), 0, stream,
                       lengths, Wf_hh, Wb_hh, pre, hping, bar, hbuf);
    hipLaunchKernelGGL(k_feats, dim3(BB * TT), dim3(64), 0, stream,
                       lengths, hbuf, Wout, bout, feats);
    hipLaunchKernelGGL(k_viterbi, dim3(BB), dim3(64), 0, stream,
                       lengths, trans, feats, bptr, out);
}